// Round 1
// baseline (327.279 us; speedup 1.0000x reference)
//
#include <hip/hip_runtime.h>
#include <stdint.h>

// Problem constants
constexpr int Ee   = 768;
constexpr int Hh   = 12;
constexpr int Dd   = 64;
constexpr int Tt   = 2048;
constexpr int Bb   = 2;
constexpr int HIDc = 3072;
constexpr int MROWS = Bb * Tt;        // 4096
constexpr int NQKV  = 3 * Hh * Dd;    // 2304

typedef unsigned short u16;
typedef __bf16 bf16;
typedef bf16 bf16x8 __attribute__((ext_vector_type(8)));
typedef float f32x4 __attribute__((ext_vector_type(4)));

__device__ __forceinline__ u16 f2bf(float f) {
  uint32_t u = __builtin_bit_cast(uint32_t, f);
  u += 0x7fffu + ((u >> 16) & 1u);
  return (u16)(u >> 16);
}

__device__ __forceinline__ f32x4 mfma16(bf16x8 a, bf16x8 b, f32x4 c) {
  return __builtin_amdgcn_mfma_f32_16x16x32_bf16(a, b, c, 0, 0, 0);
}

#define GLOAD_LDS16(gp, lp)                                                            \
  __builtin_amdgcn_global_load_lds((const __attribute__((address_space(1))) void*)(gp),\
                                   (__attribute__((address_space(3))) void*)(lp),      \
                                   16, 0, 0)

// ---------------- conversion / layout kernels ----------------

__global__ __launch_bounds__(256) void cvt_x_kernel(const float* __restrict__ in,
                                                    u16* __restrict__ out, int n4) {
  int i = blockIdx.x * 256 + threadIdx.x;
  if (i >= n4) return;
  const float4 f = *(const float4*)(in + (size_t)i * 4);
  uint2 o;
  u16* po = (u16*)&o;
  po[0] = f2bf(f.x); po[1] = f2bf(f.y); po[2] = f2bf(f.z); po[3] = f2bf(f.w);
  *(uint2*)(out + (size_t)i * 4) = o;
}

// Wq/Wk/Wv [H,E,D] fp32 -> Wt [2304][768] bf16 (row n = output col, over e)
__global__ __launch_bounds__(256) void build_wqkv_kernel(const float* __restrict__ Wq,
                                                         const float* __restrict__ Wk,
                                                         const float* __restrict__ Wv,
                                                         u16* __restrict__ out) {
  int idx = blockIdx.x * 256 + threadIdx.x;
  if (idx >= NQKV * Ee) return;
  int nrow = idx / Ee;
  int e    = idx - nrow * Ee;
  int which = nrow / (Hh * Dd);
  int nn    = nrow - which * (Hh * Dd);
  int h = nn >> 6, d = nn & 63;
  const float* W = (which == 0) ? Wq : (which == 1) ? Wk : Wv;
  out[idx] = f2bf(W[((size_t)h * Ee + e) * Dd + d]);
}

// W1 [E,HID] -> W1t [HID][E]
__global__ __launch_bounds__(256) void build_w1t_kernel(const float* __restrict__ W1,
                                                        u16* __restrict__ out) {
  int idx = blockIdx.x * 256 + threadIdx.x;
  if (idx >= HIDc * Ee) return;
  int n = idx / Ee;
  int e = idx - n * Ee;
  out[idx] = f2bf(W1[(size_t)e * HIDc + n]);
}

// W2 [HID,E] -> W2t [E][HID]
__global__ __launch_bounds__(256) void build_w2t_kernel(const float* __restrict__ W2,
                                                        u16* __restrict__ out) {
  int idx = blockIdx.x * 256 + threadIdx.x;
  if (idx >= Ee * HIDc) return;
  int n = idx / HIDc;
  int kk = idx - n * HIDc;
  out[idx] = f2bf(W2[(size_t)kk * Ee + n]);
}

// ---------------- GEMM: C[M,N] = A[M,K](bf16) * Bt[N,K](bf16)^T ----------------
// EPI 0: scatter to q/k/v [B,H,T,D] bf16
// EPI 1: +bias, relu, bf16 row-major out
// EPI 2: +bias, fp32 row-major out
template <int EPI>
__global__ __launch_bounds__(256) void gemm_bt_kernel(
    const u16* __restrict__ A, const u16* __restrict__ Bt,
    const float* __restrict__ bias,
    u16* __restrict__ out_u, float* __restrict__ out_f,
    u16* __restrict__ qp, u16* __restrict__ kp, u16* __restrict__ vp,
    int Mdim, int Ndim, int Kdim) {
  __shared__ u16 la[128 * 32];
  __shared__ u16 lb[128 * 32];
  const int tid = threadIdx.x, lane = tid & 63, wv = tid >> 6;
  const int wm = wv >> 1, wn = wv & 1;
  const int m0 = blockIdx.y * 128, n0 = blockIdx.x * 128;
  const int l15 = lane & 15, l4 = lane >> 4;
  f32x4 acc[4][4] = {};

  for (int k0 = 0; k0 < Kdim; k0 += 32) {
#pragma unroll
    for (int j = 0; j < 2; ++j) {
      const int cbase = wv * 64 + j * 256;          // wave-uniform chunk base
      const int chunk = cbase + lane;
      const int row = chunk >> 2, ko = (chunk & 3) * 8;
      GLOAD_LDS16(A + (size_t)(m0 + row) * Kdim + k0 + ko, la + (size_t)cbase * 8);
      GLOAD_LDS16(Bt + (size_t)(n0 + row) * Kdim + k0 + ko, lb + (size_t)cbase * 8);
    }
    __syncthreads();
    bf16x8 af[4], bfr[4];
#pragma unroll
    for (int i = 0; i < 4; ++i) {
      af[i]  = *(const bf16x8*)(la + (wm * 64 + i * 16 + l15) * 32 + l4 * 8);
      bfr[i] = *(const bf16x8*)(lb + (wn * 64 + i * 16 + l15) * 32 + l4 * 8);
    }
#pragma unroll
    for (int mi = 0; mi < 4; ++mi)
#pragma unroll
      for (int ni = 0; ni < 4; ++ni)
        acc[mi][ni] = mfma16(af[mi], bfr[ni], acc[mi][ni]);
    __syncthreads();
  }

#pragma unroll
  for (int mi = 0; mi < 4; ++mi)
#pragma unroll
    for (int ni = 0; ni < 4; ++ni)
#pragma unroll
      for (int r = 0; r < 4; ++r) {
        const int m = m0 + wm * 64 + mi * 16 + l4 * 4 + r;
        const int n = n0 + wn * 64 + ni * 16 + l15;
        float val = acc[mi][ni][r];
        if constexpr (EPI == 0) {
          const int b = m >> 11, t = m & 2047;
          const int which = n / (Hh * Dd);
          const int nn = n - which * (Hh * Dd);
          const int h = nn >> 6, d = nn & 63;
          u16* dst = (which == 0) ? qp : (which == 1) ? kp : vp;
          dst[((size_t)(b * Hh + h) * Tt + t) * Dd + d] = f2bf(val);
        } else if constexpr (EPI == 1) {
          val += bias[n];
          val = fmaxf(val, 0.0f);
          out_u[(size_t)m * Ndim + n] = f2bf(val);
        } else {
          val += bias[n];
          out_f[(size_t)m * Ndim + n] = val;
        }
      }
}

// ---------------- flash attention ----------------
// grid (32, B*H); block 256 = 4 waves; each block: 64 Q-rows of one (b,h)
__global__ __launch_bounds__(256) void attn_kernel(const u16* __restrict__ q,
                                                   const u16* __restrict__ k,
                                                   const u16* __restrict__ v,
                                                   float* __restrict__ aout) {
  __shared__ u16 kl[64 * 72];        // K tile [s][d], pad 72
  __shared__ u16 vt[64 * 72];        // V^T tile [d][s], pad 72
  __shared__ u16 pl[4][16 * 72];     // per-wave P tile [row][s], pad 72
  const int tid = threadIdx.x, lane = tid & 63, w = tid >> 6;
  const int l15 = lane & 15, l4 = lane >> 4;
  const int qt = 31 - blockIdx.x;    // heavy tiles first
  const int bh = blockIdx.y;
  const int q0 = qt * 64;
  constexpr float scale = 0.125f;    // 1/sqrt(64)
  constexpr float LOG2E = 1.44269504f;

  bf16x8 qf[2];
  {
    const u16* qp = q + ((size_t)bh * Tt + q0 + w * 16 + l15) * Dd;
    qf[0] = *(const bf16x8*)(qp + l4 * 8);
    qf[1] = *(const bf16x8*)(qp + 32 + l4 * 8);
  }

  f32x4 oacc[4] = {};
  float m_run[4] = {-1e30f, -1e30f, -1e30f, -1e30f};
  float l_run[4] = {};

  for (int j = 0; j <= qt; ++j) {
    // stage K and V^T tiles
    for (int c = tid; c < 512; c += 256) {
      const int s = c >> 3, dco = (c & 7) * 8;
      const size_t gbase = ((size_t)bh * Tt + j * 64 + s) * Dd + dco;
      *(uint4*)(kl + s * 72 + dco) = *(const uint4*)(k + gbase);
      const uint4 vv4 = *(const uint4*)(v + gbase);
      const u16* pv = (const u16*)&vv4;
#pragma unroll
      for (int i = 0; i < 8; ++i) vt[(dco + i) * 72 + s] = pv[i];
    }
    __syncthreads();

    // S = Q K^T  (16x64 per wave)
    f32x4 sacc[4] = {};
#pragma unroll
    for (int ns = 0; ns < 4; ++ns)
#pragma unroll
      for (int ks = 0; ks < 2; ++ks) {
        bf16x8 kf = *(const bf16x8*)(kl + (ns * 16 + l15) * 72 + ks * 32 + l4 * 8);
        sacc[ns] = mfma16(qf[ks], kf, sacc[ns]);
      }

    float p[4][4];
#pragma unroll
    for (int ns = 0; ns < 4; ++ns)
#pragma unroll
      for (int r = 0; r < 4; ++r) {
        float sv = sacc[ns][r] * scale;
        if (j == qt) {
          const int sg = j * 64 + ns * 16 + l15;
          const int tg = q0 + w * 16 + l4 * 4 + r;
          if (sg > tg) sv = -1e30f;
        }
        p[ns][r] = sv;
      }

#pragma unroll
    for (int r = 0; r < 4; ++r) {
      float mx = fmaxf(fmaxf(p[0][r], p[1][r]), fmaxf(p[2][r], p[3][r]));
#pragma unroll
      for (int off = 1; off < 16; off <<= 1) mx = fmaxf(mx, __shfl_xor(mx, off));
      const float mn = fmaxf(m_run[r], mx);
      const float corr = exp2f((m_run[r] - mn) * LOG2E);
      m_run[r] = mn;
      float rs = 0.f;
#pragma unroll
      for (int ns = 0; ns < 4; ++ns) {
        const float pe = exp2f((p[ns][r] - mn) * LOG2E);
        p[ns][r] = pe;
        rs += pe;
      }
#pragma unroll
      for (int off = 1; off < 16; off <<= 1) rs += __shfl_xor(rs, off);
      l_run[r] = l_run[r] * corr + rs;
#pragma unroll
      for (int nd = 0; nd < 4; ++nd) oacc[nd][r] *= corr;
    }

    // stage P (per-wave)
#pragma unroll
    for (int ns = 0; ns < 4; ++ns)
#pragma unroll
      for (int r = 0; r < 4; ++r)
        pl[w][(l4 * 4 + r) * 72 + ns * 16 + l15] = f2bf(p[ns][r]);

    // O += P V
#pragma unroll
    for (int ks = 0; ks < 2; ++ks) {
      bf16x8 pf = *(const bf16x8*)(&pl[w][l15 * 72 + ks * 32 + l4 * 8]);
#pragma unroll
      for (int nd = 0; nd < 4; ++nd) {
        bf16x8 vf = *(const bf16x8*)(vt + (nd * 16 + l15) * 72 + ks * 32 + l4 * 8);
        oacc[nd] = mfma16(pf, vf, oacc[nd]);
      }
    }
    __syncthreads();
  }

  const int b = bh / Hh, h = bh - b * Hh;
#pragma unroll
  for (int nd = 0; nd < 4; ++nd)
#pragma unroll
    for (int r = 0; r < 4; ++r) {
      const int tg = q0 + w * 16 + l4 * 4 + r;
      aout[((size_t)b * Tt + tg) * Ee + h * Dd + nd * 16 + l15] =
          oacc[nd][r] / l_run[r];
    }
}

// ---------------- residual + layernorm ----------------
// one block per row; y = LN(a + b); optional bf16 copy of y
__global__ __launch_bounds__(256) void ln_kernel(const float* __restrict__ a,
                                                 const float* __restrict__ bres,
                                                 const float* __restrict__ g,
                                                 const float* __restrict__ beta,
                                                 float* __restrict__ yout,
                                                 u16* __restrict__ ybout) {
  const int m = blockIdx.x;
  const float* pa = a + (size_t)m * Ee;
  const float* pb = bres + (size_t)m * Ee;
  float vbuf[3];
  float s = 0.f, ss = 0.f;
#pragma unroll
  for (int i = 0; i < 3; ++i) {
    const int e = threadIdx.x + i * 256;
    const float t = pa[e] + pb[e];
    vbuf[i] = t;
    s += t;
    ss += t * t;
  }
#pragma unroll
  for (int off = 32; off; off >>= 1) {
    s += __shfl_xor(s, off);
    ss += __shfl_xor(ss, off);
  }
  __shared__ float rs[8], rss[8];
  const int wv = threadIdx.x >> 6, ln = threadIdx.x & 63;
  if (ln == 0) { rs[wv] = s; rss[wv] = ss; }
  __syncthreads();
  if (threadIdx.x == 0) {
    float S = 0.f, SS = 0.f;
    for (int i = 0; i < 4; ++i) { S += rs[i]; SS += rss[i]; }
    rs[4] = S; rss[4] = SS;
  }
  __syncthreads();
  const float mu = rs[4] / Ee;
  const float var = rss[4] / Ee - mu * mu;
  const float inv = rsqrtf(var + 1e-5f);
#pragma unroll
  for (int i = 0; i < 3; ++i) {
    const int e = threadIdx.x + i * 256;
    const float t = (vbuf[i] - mu) * inv * g[e] + beta[e];
    yout[(size_t)m * Ee + e] = t;
    if (ybout) ybout[(size_t)m * Ee + e] = f2bf(t);
  }
}

// ---------------- launch ----------------
extern "C" void kernel_launch(void* const* d_in, const int* in_sizes, int n_in,
                              void* d_out, int out_size, void* d_ws, size_t ws_size,
                              hipStream_t stream) {
  const float* x  = (const float*)d_in[0];
  const float* Wq = (const float*)d_in[1];
  const float* Wk = (const float*)d_in[2];
  const float* Wv = (const float*)d_in[3];
  const float* W1 = (const float*)d_in[4];
  const float* b1 = (const float*)d_in[5];
  const float* W2 = (const float*)d_in[6];
  const float* b2 = (const float*)d_in[7];
  const float* g1 = (const float*)d_in[8];
  const float* be1 = (const float*)d_in[9];
  const float* g2 = (const float*)d_in[10];
  const float* be2 = (const float*)d_in[11];
  float* out = (float*)d_out;

  char* ws = (char*)d_ws;
  size_t off = 0;
  auto alloc = [&](size_t bytes) -> char* {
    char* p = ws + off;
    off += (bytes + 255) & ~(size_t)255;
    return p;
  };
  u16* xb    = (u16*)alloc((size_t)MROWS * Ee * 2);
  u16* wqkvt = (u16*)alloc((size_t)NQKV * Ee * 2);
  u16* w1t   = (u16*)alloc((size_t)HIDc * Ee * 2);
  u16* w2t   = (u16*)alloc((size_t)Ee * HIDc * 2);
  u16* qb    = (u16*)alloc((size_t)Bb * Hh * Tt * Dd * 2);
  u16* kb    = (u16*)alloc((size_t)Bb * Hh * Tt * Dd * 2);
  u16* vb    = (u16*)alloc((size_t)Bb * Hh * Tt * Dd * 2);
  float* attn = (float*)alloc((size_t)MROWS * Ee * 4);
  float* y    = (float*)alloc((size_t)MROWS * Ee * 4);
  u16* yb     = (u16*)alloc((size_t)MROWS * Ee * 2);
  u16* hbuf   = (u16*)alloc((size_t)MROWS * HIDc * 2);
  float* mlp  = (float*)alloc((size_t)MROWS * Ee * 4);
  (void)ws_size;

  // 1. conversions
  cvt_x_kernel<<<(MROWS * Ee / 4 + 255) / 256, 256, 0, stream>>>(x, xb, MROWS * Ee / 4);
  build_wqkv_kernel<<<(NQKV * Ee + 255) / 256, 256, 0, stream>>>(Wq, Wk, Wv, wqkvt);
  build_w1t_kernel<<<(HIDc * Ee + 255) / 256, 256, 0, stream>>>(W1, w1t);
  build_w2t_kernel<<<(Ee * HIDc + 255) / 256, 256, 0, stream>>>(W2, w2t);

  // 2. QKV projection
  gemm_bt_kernel<0><<<dim3(NQKV / 128, MROWS / 128), 256, 0, stream>>>(
      xb, wqkvt, nullptr, nullptr, nullptr, qb, kb, vb, MROWS, NQKV, Ee);

  // 3. attention
  attn_kernel<<<dim3(32, Bb * Hh), 256, 0, stream>>>(qb, kb, vb, attn);

  // 4. LN1
  ln_kernel<<<MROWS, 256, 0, stream>>>(x, attn, g1, be1, y, yb);

  // 5. MLP
  gemm_bt_kernel<1><<<dim3(HIDc / 128, MROWS / 128), 256, 0, stream>>>(
      yb, w1t, b1, hbuf, nullptr, nullptr, nullptr, nullptr, MROWS, HIDc, Ee);
  gemm_bt_kernel<2><<<dim3(Ee / 128, MROWS / 128), 256, 0, stream>>>(
      hbuf, w2t, b2, nullptr, mlp, nullptr, nullptr, nullptr, MROWS, Ee, HIDc);

  // 6. LN2 -> output
  ln_kernel<<<MROWS, 256, 0, stream>>>(y, mlp, g2, be2, out, nullptr);
}

// Round 2
// 272.059 us; speedup vs baseline: 1.2030x; 1.2030x over previous
//
#include <hip/hip_runtime.h>
#include <stdint.h>

// Problem constants
constexpr int Ee   = 768;
constexpr int Hh   = 12;
constexpr int Dd   = 64;
constexpr int Tt   = 2048;
constexpr int Bb   = 2;
constexpr int HIDc = 3072;
constexpr int MROWS = Bb * Tt;        // 4096
constexpr int NQKV  = 3 * Hh * Dd;    // 2304

typedef unsigned short u16;
typedef __bf16 bf16;
typedef bf16 bf16x8 __attribute__((ext_vector_type(8)));
typedef float f32x4 __attribute__((ext_vector_type(4)));

__device__ __forceinline__ u16 f2bf(float f) {
  uint32_t u = __builtin_bit_cast(uint32_t, f);
  u += 0x7fffu + ((u >> 16) & 1u);
  return (u16)(u >> 16);
}

__device__ __forceinline__ f32x4 mfma16(bf16x8 a, bf16x8 b, f32x4 c) {
  return __builtin_amdgcn_mfma_f32_16x16x32_bf16(a, b, c, 0, 0, 0);
}

#define GLOAD_LDS16(gp, lp)                                                            \
  __builtin_amdgcn_global_load_lds((const __attribute__((address_space(1))) void*)(gp),\
                                   (__attribute__((address_space(3))) void*)(lp),      \
                                   16, 0, 0)

// ---------------- conversion / layout kernels ----------------

__global__ __launch_bounds__(256) void cvt_x_kernel(const float* __restrict__ in,
                                                    u16* __restrict__ out, int n4) {
  int i = blockIdx.x * 256 + threadIdx.x;
  if (i >= n4) return;
  const float4 f = *(const float4*)(in + (size_t)i * 4);
  uint2 o;
  u16* po = (u16*)&o;
  po[0] = f2bf(f.x); po[1] = f2bf(f.y); po[2] = f2bf(f.z); po[3] = f2bf(f.w);
  *(uint2*)(out + (size_t)i * 4) = o;
}

// Wq/Wk/Wv [H,E,D] fp32 -> Wt [2304][768] bf16 (row n = output col, over e)
__global__ __launch_bounds__(256) void build_wqkv_kernel(const float* __restrict__ Wq,
                                                         const float* __restrict__ Wk,
                                                         const float* __restrict__ Wv,
                                                         u16* __restrict__ out) {
  int idx = blockIdx.x * 256 + threadIdx.x;
  if (idx >= NQKV * Ee) return;
  int nrow = idx / Ee;
  int e    = idx - nrow * Ee;
  int which = nrow / (Hh * Dd);
  int nn    = nrow - which * (Hh * Dd);
  int h = nn >> 6, d = nn & 63;
  const float* W = (which == 0) ? Wq : (which == 1) ? Wk : Wv;
  out[idx] = f2bf(W[((size_t)h * Ee + e) * Dd + d]);
}

// W1 [E,HID] -> W1t [HID][E]
__global__ __launch_bounds__(256) void build_w1t_kernel(const float* __restrict__ W1,
                                                        u16* __restrict__ out) {
  int idx = blockIdx.x * 256 + threadIdx.x;
  if (idx >= HIDc * Ee) return;
  int n = idx / Ee;
  int e = idx - n * Ee;
  out[idx] = f2bf(W1[(size_t)e * HIDc + n]);
}

// W2 [HID,E] -> W2t [E][HID]
__global__ __launch_bounds__(256) void build_w2t_kernel(const float* __restrict__ W2,
                                                        u16* __restrict__ out) {
  int idx = blockIdx.x * 256 + threadIdx.x;
  if (idx >= Ee * HIDc) return;
  int n = idx / HIDc;
  int kk = idx - n * HIDc;
  out[idx] = f2bf(W2[(size_t)kk * Ee + n]);
}

// ---------------- GEMM: C[M,N] = A[M,K](bf16) * Bt[N,K](bf16)^T ----------------
// EPI 0: scatter to q/k [B,H,T,D] bf16, v TRANSPOSED [B,H,D,T] bf16
// EPI 1: +bias, relu, bf16 row-major out
// EPI 2: +bias, fp32 row-major out
template <int EPI>
__global__ __launch_bounds__(256) void gemm_bt_kernel(
    const u16* __restrict__ A, const u16* __restrict__ Bt,
    const float* __restrict__ bias,
    u16* __restrict__ out_u, float* __restrict__ out_f,
    u16* __restrict__ qp, u16* __restrict__ kp, u16* __restrict__ vp,
    int Mdim, int Ndim, int Kdim) {
  __shared__ u16 la[128 * 32];
  __shared__ u16 lb[128 * 32];
  const int tid = threadIdx.x, lane = tid & 63, wv = tid >> 6;
  const int wm = wv >> 1, wn = wv & 1;
  const int m0 = blockIdx.y * 128, n0 = blockIdx.x * 128;
  const int l15 = lane & 15, l4 = lane >> 4;
  f32x4 acc[4][4] = {};

  for (int k0 = 0; k0 < Kdim; k0 += 32) {
#pragma unroll
    for (int j = 0; j < 2; ++j) {
      const int cbase = wv * 64 + j * 256;          // wave-uniform chunk base
      const int chunk = cbase + lane;
      const int row = chunk >> 2, ko = (chunk & 3) * 8;
      GLOAD_LDS16(A + (size_t)(m0 + row) * Kdim + k0 + ko, la + (size_t)cbase * 8);
      GLOAD_LDS16(Bt + (size_t)(n0 + row) * Kdim + k0 + ko, lb + (size_t)cbase * 8);
    }
    __syncthreads();
    bf16x8 af[4], bfr[4];
#pragma unroll
    for (int i = 0; i < 4; ++i) {
      af[i]  = *(const bf16x8*)(la + (wm * 64 + i * 16 + l15) * 32 + l4 * 8);
      bfr[i] = *(const bf16x8*)(lb + (wn * 64 + i * 16 + l15) * 32 + l4 * 8);
    }
#pragma unroll
    for (int mi = 0; mi < 4; ++mi)
#pragma unroll
      for (int ni = 0; ni < 4; ++ni)
        acc[mi][ni] = mfma16(af[mi], bfr[ni], acc[mi][ni]);
    __syncthreads();
  }

#pragma unroll
  for (int mi = 0; mi < 4; ++mi)
#pragma unroll
    for (int ni = 0; ni < 4; ++ni)
#pragma unroll
      for (int r = 0; r < 4; ++r) {
        const int m = m0 + wm * 64 + mi * 16 + l4 * 4 + r;
        const int n = n0 + wn * 64 + ni * 16 + l15;
        float val = acc[mi][ni][r];
        if constexpr (EPI == 0) {
          const int b = m >> 11, t = m & 2047;
          const int which = n / (Hh * Dd);
          const int nn = n - which * (Hh * Dd);
          const int h = nn >> 6, d = nn & 63;
          if (which == 2) {
            vp[((size_t)(b * Hh + h) * Dd + d) * Tt + t] = f2bf(val);
          } else {
            u16* dst = (which == 0) ? qp : kp;
            dst[((size_t)(b * Hh + h) * Tt + t) * Dd + d] = f2bf(val);
          }
        } else if constexpr (EPI == 1) {
          val += bias[n];
          val = fmaxf(val, 0.0f);
          out_u[(size_t)m * Ndim + n] = f2bf(val);
        } else {
          val += bias[n];
          out_f[(size_t)m * Ndim + n] = val;
        }
      }
}

// ---------------- flash attention (no-max softmax, ones-column l) ----------------
// 1-D grid of 384 blocks; block = 4 waves; 128 Q-rows/block, 32/wave.
// bid mapping: x=bid&7 (XCD pin), k=bid>>3, g=k%3, qt=15-k/3 (heavy first), bh=g*8+x
__global__ __launch_bounds__(256) void attn_kernel(const u16* __restrict__ q,
                                                   const u16* __restrict__ k,
                                                   const u16* __restrict__ vtg,
                                                   float* __restrict__ aout) {
  __shared__ u16 kl[64 * 72];       // K tile [s][d], pad 72
  __shared__ u16 vt[80 * 72];       // V^T tile [d][s] rows 0..63; row 64 = ones; 65..79 zero
  __shared__ u16 pl[4][32 * 68];    // per-wave P tile [t_loc][s], pad 68
  const int tid = threadIdx.x, lane = tid & 63, w = tid >> 6;
  const int l15 = lane & 15, l4 = lane >> 4;
  const int bid = blockIdx.x;
  const int x8 = bid & 7, kk = bid >> 3;
  const int g = kk % 3, qt = 15 - kk / 3;
  const int bh = g * 8 + x8;
  const int q0 = qt * 128;
  const int ntiles = 2 * qt + 2;
  constexpr float SC = 0.18033688f;   // log2(e)/8

  const u16* kgb = q ? k + (size_t)bh * Tt * Dd : nullptr;
  const u16* vgb = vtg + (size_t)bh * Dd * Tt;

  // Q fragments (32 rows x 64 d per wave)
  bf16x8 qf[2][2];
#pragma unroll
  for (int mf = 0; mf < 2; ++mf)
#pragma unroll
    for (int kd = 0; kd < 2; ++kd)
      qf[mf][kd] = *(const bf16x8*)(q + ((size_t)bh * Tt + q0 + w * 32 + mf * 16 + l15) * Dd +
                                    kd * 32 + l4 * 8);

  // staging assignment: 2 K-chunks + 2 V-chunks of 16B per thread
  const int c0 = tid, c1 = tid + 256;
  const int r0 = c0 >> 3, o0 = (c0 & 7) * 8;
  const int r1 = c1 >> 3, o1 = (c1 & 7) * 8;

  // init vt const rows (64 = ones, 65..79 = zero)
  for (int i = tid; i < 16 * 72; i += 256) {
    const int rr = i / 72, cc = i - rr * 72;
    vt[(64 + rr) * 72 + cc] = (rr == 0 && cc < 64) ? (u16)0x3F80 : (u16)0;
  }
  // stage tile 0
  {
    uint4 ka  = *(const uint4*)(kgb + (size_t)r0 * Dd + o0);
    uint4 kb2 = *(const uint4*)(kgb + (size_t)r1 * Dd + o1);
    uint4 va  = *(const uint4*)(vgb + (size_t)r0 * Tt + o0);
    uint4 vb2 = *(const uint4*)(vgb + (size_t)r1 * Tt + o1);
    *(uint4*)(kl + r0 * 72 + o0) = ka;
    *(uint4*)(kl + r1 * 72 + o1) = kb2;
    *(uint4*)(vt + r0 * 72 + o0) = va;
    *(uint4*)(vt + r1 * 72 + o1) = vb2;
  }
  __syncthreads();

  f32x4 oacc[2][4] = {};
  f32x4 lacc[2] = {};
  u16* plw = &pl[w][0];

  for (int j = 0;; ++j) {
    const bool more = (j + 1 < ntiles);
    uint4 ka, kb2, va, vb2;
    if (more) {   // T14: issue next-tile loads before compute
      const int s0n = (j + 1) * 64;
      ka  = *(const uint4*)(kgb + (size_t)(s0n + r0) * Dd + o0);
      kb2 = *(const uint4*)(kgb + (size_t)(s0n + r1) * Dd + o1);
      va  = *(const uint4*)(vgb + (size_t)r0 * Tt + s0n + o0);
      vb2 = *(const uint4*)(vgb + (size_t)r1 * Tt + s0n + o1);
    }

    // ---- S = Q K^T (32x64 per wave) ----
    f32x4 sacc[2][4] = {};
#pragma unroll
    for (int ns = 0; ns < 4; ++ns) {
      const bf16x8 kf0 = *(const bf16x8*)(kl + (ns * 16 + l15) * 72 + l4 * 8);
      const bf16x8 kf1 = *(const bf16x8*)(kl + (ns * 16 + l15) * 72 + 32 + l4 * 8);
      sacc[0][ns] = mfma16(qf[0][0], kf0, sacc[0][ns]);
      sacc[0][ns] = mfma16(qf[0][1], kf1, sacc[0][ns]);
      sacc[1][ns] = mfma16(qf[1][0], kf0, sacc[1][ns]);
      sacc[1][ns] = mfma16(qf[1][1], kf1, sacc[1][ns]);
    }

    // ---- P = exp(S/8), no max subtraction; write per-wave P tile ----
    if (j >= 2 * qt) {   // diagonal tiles: causal mask
#pragma unroll
      for (int mf = 0; mf < 2; ++mf)
#pragma unroll
        for (int ns = 0; ns < 4; ++ns)
#pragma unroll
          for (int r = 0; r < 4; ++r) {
            const int sg = j * 64 + ns * 16 + l15;
            const int tg = q0 + w * 32 + mf * 16 + l4 * 4 + r;
            const float pe = (sg > tg) ? 0.f : exp2f(sacc[mf][ns][r] * SC);
            *(bf16*)&plw[(mf * 16 + l4 * 4 + r) * 68 + ns * 16 + l15] = (bf16)pe;
          }
    } else {
#pragma unroll
      for (int mf = 0; mf < 2; ++mf)
#pragma unroll
        for (int ns = 0; ns < 4; ++ns)
#pragma unroll
          for (int r = 0; r < 4; ++r) {
            const float pe = exp2f(sacc[mf][ns][r] * SC);
            *(bf16*)&plw[(mf * 16 + l4 * 4 + r) * 68 + ns * 16 + l15] = (bf16)pe;
          }
    }

    // ---- O += P V ; l += P 1 (ones column) ----
#pragma unroll
    for (int ks = 0; ks < 2; ++ks) {
      bf16x8 vf[4];
#pragma unroll
      for (int nd = 0; nd < 4; ++nd)
        vf[nd] = *(const bf16x8*)(vt + (nd * 16 + l15) * 72 + ks * 32 + l4 * 8);
      const bf16x8 lf = *(const bf16x8*)(vt + (64 + l15) * 72 + ks * 32 + l4 * 8);
#pragma unroll
      for (int mf = 0; mf < 2; ++mf) {
        const bf16x8 pf = *(const bf16x8*)(plw + (mf * 16 + l15) * 68 + ks * 32 + l4 * 8);
#pragma unroll
        for (int nd = 0; nd < 4; ++nd)
          oacc[mf][nd] = mfma16(pf, vf[nd], oacc[mf][nd]);
        lacc[mf] = mfma16(pf, lf, lacc[mf]);
      }
    }

    if (!more) break;
    __syncthreads();                 // all reads of kl/vt done
    *(uint4*)(kl + r0 * 72 + o0) = ka;
    *(uint4*)(kl + r1 * 72 + o1) = kb2;
    *(uint4*)(vt + r0 * 72 + o0) = va;
    *(uint4*)(vt + r1 * 72 + o1) = vb2;
    __syncthreads();                 // next tile visible
  }

  // ---- normalize + store ----
  const int b = bh / Hh, h = bh - (bh / Hh) * Hh;
#pragma unroll
  for (int mf = 0; mf < 2; ++mf)
#pragma unroll
    for (int r = 0; r < 4; ++r) {
      const float lv = __shfl(lacc[mf][r], lane & 48);   // broadcast from l15==0 lane
      const float inv = 1.0f / lv;
      const int tg = q0 + w * 32 + mf * 16 + l4 * 4 + r;
#pragma unroll
      for (int nd = 0; nd < 4; ++nd)
        aout[((size_t)b * Tt + tg) * Ee + h * Dd + nd * 16 + l15] = oacc[mf][nd][r] * inv;
    }
}

// ---------------- residual + layernorm ----------------
__global__ __launch_bounds__(256) void ln_kernel(const float* __restrict__ a,
                                                 const float* __restrict__ bres,
                                                 const float* __restrict__ g,
                                                 const float* __restrict__ beta,
                                                 float* __restrict__ yout,
                                                 u16* __restrict__ ybout) {
  const int m = blockIdx.x;
  const float* pa = a + (size_t)m * Ee;
  const float* pb = bres + (size_t)m * Ee;
  float vbuf[3];
  float s = 0.f, ss = 0.f;
#pragma unroll
  for (int i = 0; i < 3; ++i) {
    const int e = threadIdx.x + i * 256;
    const float t = pa[e] + pb[e];
    vbuf[i] = t;
    s += t;
    ss += t * t;
  }
#pragma unroll
  for (int off = 32; off; off >>= 1) {
    s += __shfl_xor(s, off);
    ss += __shfl_xor(ss, off);
  }
  __shared__ float rs[8], rss[8];
  const int wv = threadIdx.x >> 6, ln = threadIdx.x & 63;
  if (ln == 0) { rs[wv] = s; rss[wv] = ss; }
  __syncthreads();
  if (threadIdx.x == 0) {
    float S = 0.f, SS = 0.f;
    for (int i = 0; i < 4; ++i) { S += rs[i]; SS += rss[i]; }
    rs[4] = S; rss[4] = SS;
  }
  __syncthreads();
  const float mu = rs[4] / Ee;
  const float var = rss[4] / Ee - mu * mu;
  const float inv = rsqrtf(var + 1e-5f);
#pragma unroll
  for (int i = 0; i < 3; ++i) {
    const int e = threadIdx.x + i * 256;
    const float t = (vbuf[i] - mu) * inv * g[e] + beta[e];
    yout[(size_t)m * Ee + e] = t;
    if (ybout) ybout[(size_t)m * Ee + e] = f2bf(t);
  }
}

// ---------------- launch ----------------
extern "C" void kernel_launch(void* const* d_in, const int* in_sizes, int n_in,
                              void* d_out, int out_size, void* d_ws, size_t ws_size,
                              hipStream_t stream) {
  const float* x  = (const float*)d_in[0];
  const float* Wq = (const float*)d_in[1];
  const float* Wk = (const float*)d_in[2];
  const float* Wv = (const float*)d_in[3];
  const float* W1 = (const float*)d_in[4];
  const float* b1 = (const float*)d_in[5];
  const float* W2 = (const float*)d_in[6];
  const float* b2 = (const float*)d_in[7];
  const float* g1 = (const float*)d_in[8];
  const float* be1 = (const float*)d_in[9];
  const float* g2 = (const float*)d_in[10];
  const float* be2 = (const float*)d_in[11];
  float* out = (float*)d_out;

  char* ws = (char*)d_ws;
  size_t off = 0;
  auto alloc = [&](size_t bytes) -> char* {
    char* p = ws + off;
    off += (bytes + 255) & ~(size_t)255;
    return p;
  };
  u16* xb    = (u16*)alloc((size_t)MROWS * Ee * 2);
  u16* wqkvt = (u16*)alloc((size_t)NQKV * Ee * 2);
  u16* w1t   = (u16*)alloc((size_t)HIDc * Ee * 2);
  u16* w2t   = (u16*)alloc((size_t)Ee * HIDc * 2);
  u16* qb    = (u16*)alloc((size_t)Bb * Hh * Tt * Dd * 2);
  u16* kb    = (u16*)alloc((size_t)Bb * Hh * Tt * Dd * 2);
  u16* vb    = (u16*)alloc((size_t)Bb * Hh * Tt * Dd * 2);   // [B,H,D,T]
  float* attn = (float*)alloc((size_t)MROWS * Ee * 4);
  float* y    = (float*)alloc((size_t)MROWS * Ee * 4);
  u16* yb     = (u16*)alloc((size_t)MROWS * Ee * 2);
  u16* hbuf   = (u16*)alloc((size_t)MROWS * HIDc * 2);
  float* mlp  = (float*)alloc((size_t)MROWS * Ee * 4);
  (void)ws_size;

  // 1. conversions
  cvt_x_kernel<<<(MROWS * Ee / 4 + 255) / 256, 256, 0, stream>>>(x, xb, MROWS * Ee / 4);
  build_wqkv_kernel<<<(NQKV * Ee + 255) / 256, 256, 0, stream>>>(Wq, Wk, Wv, wqkvt);
  build_w1t_kernel<<<(HIDc * Ee + 255) / 256, 256, 0, stream>>>(W1, w1t);
  build_w2t_kernel<<<(Ee * HIDc + 255) / 256, 256, 0, stream>>>(W2, w2t);

  // 2. QKV projection (V written transposed)
  gemm_bt_kernel<0><<<dim3(NQKV / 128, MROWS / 128), 256, 0, stream>>>(
      xb, wqkvt, nullptr, nullptr, nullptr, qb, kb, vb, MROWS, NQKV, Ee);

  // 3. attention
  attn_kernel<<<384, 256, 0, stream>>>(qb, kb, vb, attn);

  // 4. LN1
  ln_kernel<<<MROWS, 256, 0, stream>>>(x, attn, g1, be1, y, yb);

  // 5. MLP
  gemm_bt_kernel<1><<<dim3(HIDc / 128, MROWS / 128), 256, 0, stream>>>(
      yb, w1t, b1, hbuf, nullptr, nullptr, nullptr, nullptr, MROWS, HIDc, Ee);
  gemm_bt_kernel<2><<<dim3(Ee / 128, MROWS / 128), 256, 0, stream>>>(
      hbuf, w2t, b2, nullptr, mlp, nullptr, nullptr, nullptr, MROWS, Ee, HIDc);

  // 6. LN2 -> output
  ln_kernel<<<MROWS, 256, 0, stream>>>(y, mlp, g2, be2, out, nullptr);
}

// Round 3
// 222.431 us; speedup vs baseline: 1.4714x; 1.2231x over previous
//
#include <hip/hip_runtime.h>
#include <stdint.h>

// Problem constants
constexpr int Ee   = 768;
constexpr int Hh   = 12;
constexpr int Dd   = 64;
constexpr int Tt   = 2048;
constexpr int Bb   = 2;
constexpr int HIDc = 3072;
constexpr int MROWS = Bb * Tt;        // 4096
constexpr int NQKV  = 3 * Hh * Dd;    // 2304

typedef unsigned short u16;
typedef __bf16 bf16;
typedef bf16 bf16x8 __attribute__((ext_vector_type(8)));
typedef float f32x4 __attribute__((ext_vector_type(4)));

__device__ __forceinline__ u16 f2bf(float f) {
  uint32_t u = __builtin_bit_cast(uint32_t, f);
  u += 0x7fffu + ((u >> 16) & 1u);
  return (u16)(u >> 16);
}

__device__ __forceinline__ uint32_t cvt_pk_bf16(float lo, float hi) {
  uint32_t r;
  asm("v_cvt_pk_bf16_f32 %0, %1, %2" : "=v"(r) : "v"(lo), "v"(hi));
  return r;
}

__device__ __forceinline__ f32x4 mfma16(bf16x8 a, bf16x8 b, f32x4 c) {
  return __builtin_amdgcn_mfma_f32_16x16x32_bf16(a, b, c, 0, 0, 0);
}

#define GLOAD_LDS16(gp, lp)                                                            \
  __builtin_amdgcn_global_load_lds((const __attribute__((address_space(1))) void*)(gp),\
                                   (__attribute__((address_space(3))) void*)(lp),      \
                                   16, 0, 0)

// ---------------- conversion / layout kernels ----------------

__global__ __launch_bounds__(256) void cvt_x_kernel(const float* __restrict__ in,
                                                    u16* __restrict__ out, int n4) {
  int i = blockIdx.x * 256 + threadIdx.x;
  if (i >= n4) return;
  const float4 f = *(const float4*)(in + (size_t)i * 4);
  uint2 o;
  u16* po = (u16*)&o;
  po[0] = f2bf(f.x); po[1] = f2bf(f.y); po[2] = f2bf(f.z); po[3] = f2bf(f.w);
  *(uint2*)(out + (size_t)i * 4) = o;
}

// tiled transpose: in[z][R][C] f32 -> out[(z*C + c)*R + r] bf16 (coalesced both sides)
__global__ __launch_bounds__(256) void tr_kernel(const float* __restrict__ in,
                                                 u16* __restrict__ out,
                                                 int R, int C) {
  __shared__ float t[32][33];
  const int tx = threadIdx.x & 31, ty = threadIdx.x >> 5;   // ty 0..7
  const int r0 = blockIdx.y * 32, c0 = blockIdx.x * 32;
  const float* ip = in + (size_t)blockIdx.z * R * C;
#pragma unroll
  for (int i = 0; i < 4; ++i)
    t[ty * 4 + i][tx] = ip[(size_t)(r0 + ty * 4 + i) * C + c0 + tx];
  __syncthreads();
  u16* op = out + (size_t)blockIdx.z * C * R;
#pragma unroll
  for (int i = 0; i < 4; ++i)
    op[(size_t)(c0 + ty * 4 + i) * R + r0 + tx] = f2bf(t[tx][ty * 4 + i]);
}

// ---------------- GEMM: C[M,N] = A[M,K](bf16) * Bt[N,K](bf16)^T ----------------
// EPI 0: scatter to q/k [B,H,T,D] bf16, v TRANSPOSED [B,H,D,T] bf16
// EPI 1: +bias, relu, bf16 row-major out
// EPI 2: +bias, fp32 row-major out
template <int EPI, int BN>
__global__ __launch_bounds__(256) void gemm_bt_kernel(
    const u16* __restrict__ A, const u16* __restrict__ Bt,
    const float* __restrict__ bias,
    u16* __restrict__ out_u, float* __restrict__ out_f,
    u16* __restrict__ qp, u16* __restrict__ kp, u16* __restrict__ vp,
    int Mdim, int Ndim, int Kdim) {
  constexpr int WN = BN / 64;          // waves along N (2 or 1)
  constexpr int WM = 4 / WN;           // waves along M (2 or 4)
  constexpr int MR = 128 / WM / 16;    // m-frags per wave (4 or 2)
  __shared__ u16 la[128 * 32];
  __shared__ u16 lb[BN * 32];
  const int tid = threadIdx.x, lane = tid & 63, wv = tid >> 6;
  const int wm = wv / WN, wn = wv % WN;
  const int m0 = blockIdx.y * 128, n0 = blockIdx.x * BN;
  const int l15 = lane & 15, l4 = lane >> 4;
  f32x4 acc[MR][4] = {};

  for (int k0 = 0; k0 < Kdim; k0 += 32) {
#pragma unroll
    for (int j = 0; j < 2; ++j) {
      const int cbase = wv * 64 + j * 256;
      const int chunk = cbase + lane;
      const int row = chunk >> 2, ko = (chunk & 3) * 8;
      GLOAD_LDS16(A + (size_t)(m0 + row) * Kdim + k0 + ko, la + (size_t)cbase * 8);
    }
#pragma unroll
    for (int j = 0; j < WN; ++j) {
      const int cbase = wv * 64 + j * 256;
      const int chunk = cbase + lane;
      const int row = chunk >> 2, ko = (chunk & 3) * 8;
      GLOAD_LDS16(Bt + (size_t)(n0 + row) * Kdim + k0 + ko, lb + (size_t)cbase * 8);
    }
    __syncthreads();
    bf16x8 af[MR], bfr[4];
#pragma unroll
    for (int i = 0; i < MR; ++i)
      af[i] = *(const bf16x8*)(la + (wm * (MR * 16) + i * 16 + l15) * 32 + l4 * 8);
#pragma unroll
    for (int i = 0; i < 4; ++i)
      bfr[i] = *(const bf16x8*)(lb + (wn * 64 + i * 16 + l15) * 32 + l4 * 8);
#pragma unroll
    for (int mi = 0; mi < MR; ++mi)
#pragma unroll
      for (int ni = 0; ni < 4; ++ni)
        acc[mi][ni] = mfma16(af[mi], bfr[ni], acc[mi][ni]);
    __syncthreads();
  }

#pragma unroll
  for (int mi = 0; mi < MR; ++mi)
#pragma unroll
    for (int ni = 0; ni < 4; ++ni)
#pragma unroll
      for (int r = 0; r < 4; ++r) {
        const int m = m0 + wm * (MR * 16) + mi * 16 + l4 * 4 + r;
        const int n = n0 + wn * 64 + ni * 16 + l15;
        float val = acc[mi][ni][r];
        if constexpr (EPI == 0) {
          const int b = m >> 11, t = m & 2047;
          const int which = n / (Hh * Dd);
          const int nn = n - which * (Hh * Dd);
          const int h = nn >> 6, d = nn & 63;
          if (which == 2) {
            vp[((size_t)(b * Hh + h) * Dd + d) * Tt + t] = f2bf(val);
          } else {
            u16* dst = (which == 0) ? qp : kp;
            dst[((size_t)(b * Hh + h) * Tt + t) * Dd + d] = f2bf(val);
          }
        } else if constexpr (EPI == 1) {
          val += bias[n];
          val = fmaxf(val, 0.0f);
          out_u[(size_t)m * Ndim + n] = f2bf(val);
        } else {
          val += bias[n];
          out_f[(size_t)m * Ndim + n] = val;
        }
      }
}

// ---------------- flash attention (swapped QK^T, in-register P, no-max) ----------
// grid 384; bid: x8=bid&7 (XCD pin), kk=bid>>3, g=kk%3, qt=15-kk/3, bh=g*8+x8
// block = 4 waves; 128 Q-rows/block, 32/wave. K/V LDS double-buffered, 1 barrier/iter.
__global__ __launch_bounds__(256) void attn_kernel(const u16* __restrict__ q,
                                                   const u16* __restrict__ k,
                                                   const u16* __restrict__ vtg,
                                                   float* __restrict__ aout) {
  __shared__ u16 kl[2][64 * 72];     // K tile [s][d], pad 72
  __shared__ u16 vt[2][64 * 72];     // V^T tile [d][s], pad 72
  __shared__ u16 pl[4][32 * 72];     // per-wave P tile [t_loc][s], pad 72
  const int tid = threadIdx.x, lane = tid & 63, w = tid >> 6;
  const int l15 = lane & 15, l4 = lane >> 4;
  const int bid = blockIdx.x;
  const int x8 = bid & 7, kk2 = bid >> 3;
  const int g = kk2 % 3, qt = 15 - kk2 / 3;
  const int bh = g * 8 + x8;
  const int q0 = qt * 128;
  const int ntiles = 2 * qt + 2;
  constexpr float SC = 0.18033688f;   // log2(e)/8

  const u16* kgb = k + (size_t)bh * Tt * Dd;
  const u16* vgb = vtg + (size_t)bh * Dd * Tt;

  // Q fragments (32 rows x 64 d per wave); used as MFMA B operand
  bf16x8 qf[2][2];
#pragma unroll
  for (int mf = 0; mf < 2; ++mf)
#pragma unroll
    for (int kd = 0; kd < 2; ++kd)
      qf[mf][kd] = *(const bf16x8*)(q + ((size_t)bh * Tt + q0 + w * 32 + mf * 16 + l15) * Dd +
                                    kd * 32 + l4 * 8);

  // staging: each thread 2 K-rows-chunks + 2 V-rows-chunks of 16B
  const int r0 = tid >> 3, o0 = (tid & 7) * 8;   // r0 0..31
  const int r1 = r0 + 32;

  // prologue: stage tile 0 into buffer 0
  {
    const uint4 ka  = *(const uint4*)(kgb + (size_t)r0 * Dd + o0);
    const uint4 kb2 = *(const uint4*)(kgb + (size_t)r1 * Dd + o0);
    const uint4 va  = *(const uint4*)(vgb + (size_t)r0 * Tt + o0);
    const uint4 vb2 = *(const uint4*)(vgb + (size_t)r1 * Tt + o0);
    *(uint4*)(kl[0] + r0 * 72 + o0) = ka;
    *(uint4*)(kl[0] + r1 * 72 + o0) = kb2;
    *(uint4*)(vt[0] + r0 * 72 + o0) = va;
    *(uint4*)(vt[0] + r1 * 72 + o0) = vb2;
  }

  f32x4 oacc[2][4] = {};
  float lrun[2] = {0.f, 0.f};
  u16* plw = &pl[w][0];

  for (int j = 0; j < ntiles; ++j) {
    __syncthreads();   // buf[j&1] writes visible; buf[(j+1)&1] readers done
    const int cur = j & 1;
    const bool more = (j + 1 < ntiles);
    uint4 ka, kb2, va, vb2;
    if (more) {        // T14: issue next-tile loads right after barrier
      const int s0n = (j + 1) * 64;
      ka  = *(const uint4*)(kgb + (size_t)(s0n + r0) * Dd + o0);
      kb2 = *(const uint4*)(kgb + (size_t)(s0n + r1) * Dd + o0);
      va  = *(const uint4*)(vgb + (size_t)r0 * Tt + s0n + o0);
      vb2 = *(const uint4*)(vgb + (size_t)r1 * Tt + s0n + o0);
    }
    const u16* klc = kl[cur];
    const u16* vtc = vt[cur];

    // ---- S^T = (K Q^T): A=K-frag (rows s), B=Q-frag (cols t) ----
    f32x4 sacc[2][4] = {};
#pragma unroll
    for (int ns = 0; ns < 4; ++ns) {
      const bf16x8 kf0 = *(const bf16x8*)(klc + (ns * 16 + l15) * 72 + l4 * 8);
      const bf16x8 kf1 = *(const bf16x8*)(klc + (ns * 16 + l15) * 72 + 32 + l4 * 8);
      sacc[0][ns] = mfma16(kf0, qf[0][0], sacc[0][ns]);
      sacc[0][ns] = mfma16(kf1, qf[0][1], sacc[0][ns]);
      sacc[1][ns] = mfma16(kf0, qf[1][0], sacc[1][ns]);
      sacc[1][ns] = mfma16(kf1, qf[1][1], sacc[1][ns]);
    }

    // ---- P = exp2(S^T * SC) (no max), causal mask on diagonal tiles ----
    const bool diag = (j >= 2 * qt);
#pragma unroll
    for (int mf = 0; mf < 2; ++mf) {
      const int tg = q0 + w * 32 + mf * 16 + l15;
      float pe[16];
      float rs = 0.f;
#pragma unroll
      for (int ns = 0; ns < 4; ++ns)
#pragma unroll
        for (int r = 0; r < 4; ++r) {
          float e = __builtin_amdgcn_exp2f(sacc[mf][ns][r] * SC);
          if (diag) {
            const int sg = j * 64 + ns * 16 + l4 * 4 + r;
            e = (sg > tg) ? 0.f : e;
          }
          pe[ns * 4 + r] = e;
          rs += e;
        }
      rs += __shfl_xor(rs, 16);
      rs += __shfl_xor(rs, 32);
      lrun[mf] += rs;
#pragma unroll
      for (int ns = 0; ns < 4; ++ns) {
        uint2 pw;
        pw.x = cvt_pk_bf16(pe[ns * 4 + 0], pe[ns * 4 + 1]);
        pw.y = cvt_pk_bf16(pe[ns * 4 + 2], pe[ns * 4 + 3]);
        *(uint2*)(plw + (mf * 16 + l15) * 72 + ns * 16 + l4 * 4) = pw;
      }
    }

    // ---- O^T += V^T P^T : A=V^T-frag (rows d), B=P-frag (cols t) ----
#pragma unroll
    for (int ks = 0; ks < 2; ++ks) {
      const bf16x8 pf0 = *(const bf16x8*)(plw + l15 * 72 + ks * 32 + l4 * 8);
      const bf16x8 pf1 = *(const bf16x8*)(plw + (16 + l15) * 72 + ks * 32 + l4 * 8);
#pragma unroll
      for (int nd = 0; nd < 4; ++nd) {
        const bf16x8 vf = *(const bf16x8*)(vtc + (nd * 16 + l15) * 72 + ks * 32 + l4 * 8);
        oacc[0][nd] = mfma16(vf, pf0, oacc[0][nd]);
        oacc[1][nd] = mfma16(vf, pf1, oacc[1][nd]);
      }
    }

    if (more) {   // write next tile into the other buffer (after this iter's reads)
      const int nxt = cur ^ 1;
      *(uint4*)(kl[nxt] + r0 * 72 + o0) = ka;
      *(uint4*)(kl[nxt] + r1 * 72 + o0) = kb2;
      *(uint4*)(vt[nxt] + r0 * 72 + o0) = va;
      *(uint4*)(vt[nxt] + r1 * 72 + o0) = vb2;
    }
  }

  // ---- normalize + store (O^T: lane has d = nd*16+l4*4+r, t = l15) ----
  const int b = bh / Hh, h = bh - (bh / Hh) * Hh;
#pragma unroll
  for (int mf = 0; mf < 2; ++mf) {
    const float inv = 1.0f / lrun[mf];
    const int tg = q0 + w * 32 + mf * 16 + l15;
    float* orow = aout + (size_t)(b * Tt + tg) * Ee + h * Dd;
#pragma unroll
    for (int nd = 0; nd < 4; ++nd) {
      float4 ov;
      ov.x = oacc[mf][nd][0] * inv;
      ov.y = oacc[mf][nd][1] * inv;
      ov.z = oacc[mf][nd][2] * inv;
      ov.w = oacc[mf][nd][3] * inv;
      *(float4*)(orow + nd * 16 + l4 * 4) = ov;
    }
  }
}

// ---------------- residual + layernorm ----------------
__global__ __launch_bounds__(256) void ln_kernel(const float* __restrict__ a,
                                                 const float* __restrict__ bres,
                                                 const float* __restrict__ g,
                                                 const float* __restrict__ beta,
                                                 float* __restrict__ yout,
                                                 u16* __restrict__ ybout) {
  const int m = blockIdx.x;
  const float* pa = a + (size_t)m * Ee;
  const float* pb = bres + (size_t)m * Ee;
  float vbuf[3];
  float s = 0.f, ss = 0.f;
#pragma unroll
  for (int i = 0; i < 3; ++i) {
    const int e = threadIdx.x + i * 256;
    const float t = pa[e] + pb[e];
    vbuf[i] = t;
    s += t;
    ss += t * t;
  }
#pragma unroll
  for (int off = 32; off; off >>= 1) {
    s += __shfl_xor(s, off);
    ss += __shfl_xor(ss, off);
  }
  __shared__ float rs[8], rss[8];
  const int wv = threadIdx.x >> 6, ln = threadIdx.x & 63;
  if (ln == 0) { rs[wv] = s; rss[wv] = ss; }
  __syncthreads();
  if (threadIdx.x == 0) {
    float S = 0.f, SS = 0.f;
    for (int i = 0; i < 4; ++i) { S += rs[i]; SS += rss[i]; }
    rs[4] = S; rss[4] = SS;
  }
  __syncthreads();
  const float mu = rs[4] / Ee;
  const float var = rss[4] / Ee - mu * mu;
  const float inv = rsqrtf(var + 1e-5f);
#pragma unroll
  for (int i = 0; i < 3; ++i) {
    const int e = threadIdx.x + i * 256;
    const float t = (vbuf[i] - mu) * inv * g[e] + beta[e];
    yout[(size_t)m * Ee + e] = t;
    if (ybout) ybout[(size_t)m * Ee + e] = f2bf(t);
  }
}

// ---------------- launch ----------------
extern "C" void kernel_launch(void* const* d_in, const int* in_sizes, int n_in,
                              void* d_out, int out_size, void* d_ws, size_t ws_size,
                              hipStream_t stream) {
  const float* x  = (const float*)d_in[0];
  const float* Wq = (const float*)d_in[1];
  const float* Wk = (const float*)d_in[2];
  const float* Wv = (const float*)d_in[3];
  const float* W1 = (const float*)d_in[4];
  const float* b1 = (const float*)d_in[5];
  const float* W2 = (const float*)d_in[6];
  const float* b2 = (const float*)d_in[7];
  const float* g1 = (const float*)d_in[8];
  const float* be1 = (const float*)d_in[9];
  const float* g2 = (const float*)d_in[10];
  const float* be2 = (const float*)d_in[11];
  float* out = (float*)d_out;

  char* ws = (char*)d_ws;
  size_t off = 0;
  auto alloc = [&](size_t bytes) -> char* {
    char* p = ws + off;
    off += (bytes + 255) & ~(size_t)255;
    return p;
  };
  u16* xb    = (u16*)alloc((size_t)MROWS * Ee * 2);
  u16* wqkvt = (u16*)alloc((size_t)NQKV * Ee * 2);
  u16* w1t   = (u16*)alloc((size_t)HIDc * Ee * 2);
  u16* w2t   = (u16*)alloc((size_t)Ee * HIDc * 2);
  u16* qb    = (u16*)alloc((size_t)Bb * Hh * Tt * Dd * 2);
  u16* kb    = (u16*)alloc((size_t)Bb * Hh * Tt * Dd * 2);
  u16* vb    = (u16*)alloc((size_t)Bb * Hh * Tt * Dd * 2);   // [B,H,D,T]
  float* attn = (float*)alloc((size_t)MROWS * Ee * 4);
  float* y    = (float*)alloc((size_t)MROWS * Ee * 4);
  u16* yb     = (u16*)alloc((size_t)MROWS * Ee * 2);
  u16* hbuf   = (u16*)alloc((size_t)MROWS * HIDc * 2);
  float* mlp  = (float*)alloc((size_t)MROWS * Ee * 4);
  (void)ws_size;

  // 1. conversions (all coalesced)
  cvt_x_kernel<<<(MROWS * Ee / 4 + 255) / 256, 256, 0, stream>>>(x, xb, MROWS * Ee / 4);
  // Wq/Wk/Wv [12][768][64] -> wqkvt rows [which*768 + h*64 + d][e]
  tr_kernel<<<dim3(2, 24, 12), 256, 0, stream>>>(Wq, wqkvt + 0 * (size_t)768 * Ee, Ee, Dd);
  tr_kernel<<<dim3(2, 24, 12), 256, 0, stream>>>(Wk, wqkvt + 1 * (size_t)768 * Ee, Ee, Dd);
  tr_kernel<<<dim3(2, 24, 12), 256, 0, stream>>>(Wv, wqkvt + 2 * (size_t)768 * Ee, Ee, Dd);
  // W1 [768][3072] -> w1t [3072][768]
  tr_kernel<<<dim3(96, 24, 1), 256, 0, stream>>>(W1, w1t, Ee, HIDc);
  // W2 [3072][768] -> w2t [768][3072]
  tr_kernel<<<dim3(24, 96, 1), 256, 0, stream>>>(W2, w2t, HIDc, Ee);

  // 2. QKV projection (V written transposed)
  gemm_bt_kernel<0, 128><<<dim3(NQKV / 128, MROWS / 128), 256, 0, stream>>>(
      xb, wqkvt, nullptr, nullptr, nullptr, qb, kb, vb, MROWS, NQKV, Ee);

  // 3. attention
  attn_kernel<<<384, 256, 0, stream>>>(qb, kb, vb, attn);

  // 4. LN1
  ln_kernel<<<MROWS, 256, 0, stream>>>(x, attn, g1, be1, y, yb);

  // 5. MLP
  gemm_bt_kernel<1, 128><<<dim3(HIDc / 128, MROWS / 128), 256, 0, stream>>>(
      yb, w1t, b1, hbuf, nullptr, nullptr, nullptr, nullptr, MROWS, HIDc, Ee);
  gemm_bt_kernel<2, 64><<<dim3(Ee / 64, MROWS / 128), 256, 0, stream>>>(
      hbuf, w2t, b2, nullptr, mlp, nullptr, nullptr, nullptr, MROWS, Ee, HIDc);

  // 6. LN2 -> output
  ln_kernel<<<MROWS, 256, 0, stream>>>(y, mlp, g2, be2, out, nullptr);
}

// Round 4
// 187.658 us; speedup vs baseline: 1.7440x; 1.1853x over previous
//
#include <hip/hip_runtime.h>
#include <stdint.h>

// Problem constants
constexpr int Ee   = 768;
constexpr int Hh   = 12;
constexpr int Dd   = 64;
constexpr int Tt   = 2048;
constexpr int Bb   = 2;
constexpr int HIDc = 3072;
constexpr int MROWS = Bb * Tt;        // 4096
constexpr int NQKV  = 3 * Hh * Dd;    // 2304

typedef unsigned short u16;
typedef __bf16 bf16;
typedef bf16 bf16x8 __attribute__((ext_vector_type(8)));
typedef float f32x4 __attribute__((ext_vector_type(4)));

__device__ __forceinline__ u16 f2bf(float f) {
  uint32_t u = __builtin_bit_cast(uint32_t, f);
  u += 0x7fffu + ((u >> 16) & 1u);
  return (u16)(u >> 16);
}

__device__ __forceinline__ uint32_t cvt_pk_bf16(float lo, float hi) {
  uint32_t r;
  asm("v_cvt_pk_bf16_f32 %0, %1, %2" : "=v"(r) : "v"(lo), "v"(hi));
  return r;
}

__device__ __forceinline__ f32x4 mfma16(bf16x8 a, bf16x8 b, f32x4 c) {
  return __builtin_amdgcn_mfma_f32_16x16x32_bf16(a, b, c, 0, 0, 0);
}

#define GLOAD_LDS16(gp, lp)                                                            \
  __builtin_amdgcn_global_load_lds((const __attribute__((address_space(1))) void*)(gp),\
                                   (__attribute__((address_space(3))) void*)(lp),      \
                                   16, 0, 0)

// ---------------- conversion / layout kernels ----------------

__global__ __launch_bounds__(256) void cvt_x_kernel(const float* __restrict__ in,
                                                    u16* __restrict__ out, int n4) {
  int i = blockIdx.x * 256 + threadIdx.x;
  if (i >= n4) return;
  const float4 f = *(const float4*)(in + (size_t)i * 4);
  uint2 o;
  u16* po = (u16*)&o;
  po[0] = f2bf(f.x); po[1] = f2bf(f.y); po[2] = f2bf(f.z); po[3] = f2bf(f.w);
  *(uint2*)(out + (size_t)i * 4) = o;
}

// tiled transpose: in[z][R][C] f32 -> out[z][C][R] bf16
__global__ __launch_bounds__(256) void tr_kernel(const float* __restrict__ in,
                                                 u16* __restrict__ out,
                                                 int R, int C) {
  __shared__ float t[32][33];
  const int tx = threadIdx.x & 31, ty = threadIdx.x >> 5;
  const int r0 = blockIdx.y * 32, c0 = blockIdx.x * 32;
  const float* ip = in + (size_t)blockIdx.z * R * C;
#pragma unroll
  for (int i = 0; i < 4; ++i)
    t[ty * 4 + i][tx] = ip[(size_t)(r0 + ty * 4 + i) * C + c0 + tx];
  __syncthreads();
  u16* op = out + (size_t)blockIdx.z * C * R;
#pragma unroll
  for (int i = 0; i < 4; ++i)
    op[(size_t)(c0 + ty * 4 + i) * R + r0 + tx] = f2bf(t[tx][ty * 4 + i]);
}

// Wq/Wk/Wv [12][768][64] f32 -> wqkvt [(which*768 + h*64 + d)][768] bf16
__global__ __launch_bounds__(256) void tr_qkv_kernel(const float* __restrict__ Wq,
                                                     const float* __restrict__ Wk,
                                                     const float* __restrict__ Wv,
                                                     u16* __restrict__ out) {
  __shared__ float t[32][33];
  const int tx = threadIdx.x & 31, ty = threadIdx.x >> 5;
  const int z = blockIdx.z;                 // 0..35
  const int which = z / 12, hs = z - which * 12;
  const float* W = (which == 0) ? Wq : (which == 1) ? Wk : Wv;
  const float* ip = W + (size_t)hs * Ee * Dd;              // [768][64] slice
  const int r0 = blockIdx.y * 32, c0 = blockIdx.x * 32;    // r over E, c over D
#pragma unroll
  for (int i = 0; i < 4; ++i)
    t[ty * 4 + i][tx] = ip[(size_t)(r0 + ty * 4 + i) * Dd + c0 + tx];
  __syncthreads();
  u16* op = out + ((size_t)which * 768 + hs * 64) * Ee;    // rows over D, cols over E
#pragma unroll
  for (int i = 0; i < 4; ++i)
    op[(size_t)(c0 + ty * 4 + i) * Ee + r0 + tx] = f2bf(t[tx][ty * 4 + i]);
}

// V [B*H][T][D] bf16 -> Vt [B*H][D][T] bf16
__global__ __launch_bounds__(256) void trv_kernel(const u16* __restrict__ in,
                                                  u16* __restrict__ out) {
  __shared__ u16 t[64][72];
  const int z = blockIdx.y;
  const int t0 = blockIdx.x * 64;
  const int tid = threadIdx.x;
#pragma unroll
  for (int it = 0; it < 2; ++it) {
    const int idx = it * 256 + tid;
    const int row = idx >> 3, c8 = (idx & 7) * 8;
    *(uint4*)&t[row][c8] = *(const uint4*)(in + ((size_t)z * Tt + t0 + row) * Dd + c8);
  }
  __syncthreads();
#pragma unroll
  for (int it = 0; it < 2; ++it) {
    const int idx = it * 256 + tid;
    const int d = idx >> 3, tt = (idx & 7) * 8;
    uint4 o;
    u16* po = (u16*)&o;
#pragma unroll
    for (int i = 0; i < 8; ++i) po[i] = t[tt + i][d];
    *(uint4*)(out + ((size_t)z * Dd + d) * Tt + t0 + tt) = o;
  }
}

// ---------------- GEMM: C[M,N] = A[M,K](bf16) * Bt[N,K](bf16)^T ----------------
// BK=64, XOR-swizzled LDS (T2, both-sides via inverse-swizzled global source).
// EPI 0: scatter to q/k/v [B,H,T,D] bf16
// EPI 1: +bias, relu, bf16 row-major out
// EPI 2: +bias(kz==0 only), fp32 out to partial buffer kz
template <int EPI, int BN, int SPLITK>
__global__ __launch_bounds__(256) void gemm_bt_kernel(
    const u16* __restrict__ A, const u16* __restrict__ Bt,
    const float* __restrict__ bias,
    u16* __restrict__ out_u, float* __restrict__ out_f,
    u16* __restrict__ qp, u16* __restrict__ kp, u16* __restrict__ vp,
    int Mdim, int Ndim, int Kdim, int gx, int gy) {
  constexpr int WN = BN / 64;          // waves along N (2 or 1)
  constexpr int WM = 4 / WN;           // waves along M (2 or 4)
  constexpr int MR = 128 / WM / 16;    // m-frags per wave (4 or 2)
  constexpr int ACH = 16;              // A chunks of 1KB
  constexpr int BCH = BN / 8;          // B chunks of 1KB
  __shared__ u16 la[128 * 64];
  __shared__ u16 lb[BN * 64];
  const int tid = threadIdx.x, lane = tid & 63, wv = tid >> 6;
  const int wm = wv / WN, wn = wv % WN;
  const int l15 = lane & 15, l4 = lane >> 4;

  // chunked XCD swizzle: consecutive wg on one XCD, bx fastest (A-panel reuse)
  const int nwg = gx * gy * SPLITK;
  const int cpx = nwg >> 3;
  const int wg = (blockIdx.x & 7) * cpx + (blockIdx.x >> 3);
  const int bx = wg % gx;
  const int byz = wg / gx;
  const int by = byz % gy;
  const int kz = byz / gy;
  const int m0 = by * 128, n0 = bx * BN;
  const int Ks = Kdim / SPLITK;
  const int kend = (kz + 1) * Ks;

  // per-lane inverse-swizzle staging coordinates (chunk-relative)
  // beta = (cb + lane)*16 ; row = (cb+lane)>>3 ; kb_log = (beta&127) ^ ((row&7)<<4)
  f32x4 acc[MR][4] = {};

  for (int k0 = kz * Ks; k0 < kend; k0 += 64) {
#pragma unroll
    for (int j = 0; j < ACH / 4; ++j) {
      const int cb = (wv * (ACH / 4) + j) * 64;
      const int ci = cb + lane;
      const int row = ci >> 3;
      const int kbl = ((ci & 7) * 16) ^ ((row & 7) << 4);
      GLOAD_LDS16(A + (size_t)(m0 + row) * Kdim + k0 + (kbl >> 1), la + (size_t)cb * 8);
    }
#pragma unroll
    for (int j = 0; j < BCH / 4; ++j) {
      const int cb = (wv * (BCH / 4) + j) * 64;
      const int ci = cb + lane;
      const int row = ci >> 3;
      const int kbl = ((ci & 7) * 16) ^ ((row & 7) << 4);
      GLOAD_LDS16(Bt + (size_t)(n0 + row) * Kdim + k0 + (kbl >> 1), lb + (size_t)cb * 8);
    }
    __syncthreads();
#pragma unroll
    for (int ks = 0; ks < 2; ++ks) {
      bf16x8 af[MR], bfr[4];
#pragma unroll
      for (int i = 0; i < MR; ++i) {
        const int row = wm * (MR * 16) + i * 16 + l15;
        af[i] = *(const bf16x8*)((const char*)la + row * 128 +
                                 (((ks * 64 + l4 * 16)) ^ ((row & 7) << 4)));
      }
#pragma unroll
      for (int i = 0; i < 4; ++i) {
        const int row = wn * 64 + i * 16 + l15;
        bfr[i] = *(const bf16x8*)((const char*)lb + row * 128 +
                                  (((ks * 64 + l4 * 16)) ^ ((row & 7) << 4)));
      }
#pragma unroll
      for (int mi = 0; mi < MR; ++mi)
#pragma unroll
        for (int ni = 0; ni < 4; ++ni)
          acc[mi][ni] = mfma16(af[mi], bfr[ni], acc[mi][ni]);
    }
    __syncthreads();
  }

#pragma unroll
  for (int mi = 0; mi < MR; ++mi)
#pragma unroll
    for (int ni = 0; ni < 4; ++ni)
#pragma unroll
      for (int r = 0; r < 4; ++r) {
        const int m = m0 + wm * (MR * 16) + mi * 16 + l4 * 4 + r;
        const int n = n0 + wn * 64 + ni * 16 + l15;
        float val = acc[mi][ni][r];
        if constexpr (EPI == 0) {
          const int b = m >> 11, t = m & 2047;
          const int which = n / (Hh * Dd);
          const int nn = n - which * (Hh * Dd);
          const int h = nn >> 6, d = nn & 63;
          u16* dst = (which == 0) ? qp : (which == 1) ? kp : vp;
          dst[((size_t)(b * Hh + h) * Tt + t) * Dd + d] = f2bf(val);
        } else if constexpr (EPI == 1) {
          val += bias[n];
          val = fmaxf(val, 0.0f);
          out_u[(size_t)m * Ndim + n] = f2bf(val);
        } else {
          if (kz == 0) val += bias[n];
          out_f[(size_t)kz * Mdim * Ndim + (size_t)m * Ndim + n] = val;
        }
      }
}

// ---------------- flash attention (swapped QK^T, in-register P, no-max) ----------
__global__ __launch_bounds__(256) void attn_kernel(const u16* __restrict__ q,
                                                   const u16* __restrict__ k,
                                                   const u16* __restrict__ vtg,
                                                   float* __restrict__ aout) {
  __shared__ u16 kl[2][64 * 72];
  __shared__ u16 vt[2][64 * 72];
  __shared__ u16 pl[4][32 * 72];
  const int tid = threadIdx.x, lane = tid & 63, w = tid >> 6;
  const int l15 = lane & 15, l4 = lane >> 4;
  const int bid = blockIdx.x;
  const int x8 = bid & 7, kk2 = bid >> 3;
  const int g = kk2 % 3, qt = 15 - kk2 / 3;
  const int bh = g * 8 + x8;
  const int q0 = qt * 128;
  const int ntiles = 2 * qt + 2;
  constexpr float SC = 0.18033688f;   // log2(e)/8

  const u16* kgb = k + (size_t)bh * Tt * Dd;
  const u16* vgb = vtg + (size_t)bh * Dd * Tt;

  bf16x8 qf[2][2];
#pragma unroll
  for (int mf = 0; mf < 2; ++mf)
#pragma unroll
    for (int kd = 0; kd < 2; ++kd)
      qf[mf][kd] = *(const bf16x8*)(q + ((size_t)bh * Tt + q0 + w * 32 + mf * 16 + l15) * Dd +
                                    kd * 32 + l4 * 8);

  const int r0 = tid >> 3, o0 = (tid & 7) * 8;
  const int r1 = r0 + 32;

  {
    const uint4 ka  = *(const uint4*)(kgb + (size_t)r0 * Dd + o0);
    const uint4 kb2 = *(const uint4*)(kgb + (size_t)r1 * Dd + o0);
    const uint4 va  = *(const uint4*)(vgb + (size_t)r0 * Tt + o0);
    const uint4 vb2 = *(const uint4*)(vgb + (size_t)r1 * Tt + o0);
    *(uint4*)(kl[0] + r0 * 72 + o0) = ka;
    *(uint4*)(kl[0] + r1 * 72 + o0) = kb2;
    *(uint4*)(vt[0] + r0 * 72 + o0) = va;
    *(uint4*)(vt[0] + r1 * 72 + o0) = vb2;
  }

  f32x4 oacc[2][4] = {};
  float lrun[2] = {0.f, 0.f};
  u16* plw = &pl[w][0];

  for (int j = 0; j < ntiles; ++j) {
    __syncthreads();
    const int cur = j & 1;
    const bool more = (j + 1 < ntiles);
    uint4 ka, kb2, va, vb2;
    if (more) {
      const int s0n = (j + 1) * 64;
      ka  = *(const uint4*)(kgb + (size_t)(s0n + r0) * Dd + o0);
      kb2 = *(const uint4*)(kgb + (size_t)(s0n + r1) * Dd + o0);
      va  = *(const uint4*)(vgb + (size_t)r0 * Tt + s0n + o0);
      vb2 = *(const uint4*)(vgb + (size_t)r1 * Tt + s0n + o0);
    }
    const u16* klc = kl[cur];
    const u16* vtc = vt[cur];

    f32x4 sacc[2][4] = {};
#pragma unroll
    for (int ns = 0; ns < 4; ++ns) {
      const bf16x8 kf0 = *(const bf16x8*)(klc + (ns * 16 + l15) * 72 + l4 * 8);
      const bf16x8 kf1 = *(const bf16x8*)(klc + (ns * 16 + l15) * 72 + 32 + l4 * 8);
      sacc[0][ns] = mfma16(kf0, qf[0][0], sacc[0][ns]);
      sacc[0][ns] = mfma16(kf1, qf[0][1], sacc[0][ns]);
      sacc[1][ns] = mfma16(kf0, qf[1][0], sacc[1][ns]);
      sacc[1][ns] = mfma16(kf1, qf[1][1], sacc[1][ns]);
    }

    const bool diag = (j >= 2 * qt);
#pragma unroll
    for (int mf = 0; mf < 2; ++mf) {
      const int tg = q0 + w * 32 + mf * 16 + l15;
      float pe[16];
      float rs = 0.f;
#pragma unroll
      for (int ns = 0; ns < 4; ++ns)
#pragma unroll
        for (int r = 0; r < 4; ++r) {
          float e = __builtin_amdgcn_exp2f(sacc[mf][ns][r] * SC);
          if (diag) {
            const int sg = j * 64 + ns * 16 + l4 * 4 + r;
            e = (sg > tg) ? 0.f : e;
          }
          pe[ns * 4 + r] = e;
          rs += e;
        }
      rs += __shfl_xor(rs, 16);
      rs += __shfl_xor(rs, 32);
      lrun[mf] += rs;
#pragma unroll
      for (int ns = 0; ns < 4; ++ns) {
        uint2 pw;
        pw.x = cvt_pk_bf16(pe[ns * 4 + 0], pe[ns * 4 + 1]);
        pw.y = cvt_pk_bf16(pe[ns * 4 + 2], pe[ns * 4 + 3]);
        *(uint2*)(plw + (mf * 16 + l15) * 72 + ns * 16 + l4 * 4) = pw;
      }
    }

#pragma unroll
    for (int ks = 0; ks < 2; ++ks) {
      const bf16x8 pf0 = *(const bf16x8*)(plw + l15 * 72 + ks * 32 + l4 * 8);
      const bf16x8 pf1 = *(const bf16x8*)(plw + (16 + l15) * 72 + ks * 32 + l4 * 8);
#pragma unroll
      for (int nd = 0; nd < 4; ++nd) {
        const bf16x8 vf = *(const bf16x8*)(vtc + (nd * 16 + l15) * 72 + ks * 32 + l4 * 8);
        oacc[0][nd] = mfma16(vf, pf0, oacc[0][nd]);
        oacc[1][nd] = mfma16(vf, pf1, oacc[1][nd]);
      }
    }

    if (more) {
      const int nxt = cur ^ 1;
      *(uint4*)(kl[nxt] + r0 * 72 + o0) = ka;
      *(uint4*)(kl[nxt] + r1 * 72 + o0) = kb2;
      *(uint4*)(vt[nxt] + r0 * 72 + o0) = va;
      *(uint4*)(vt[nxt] + r1 * 72 + o0) = vb2;
    }
  }

  const int b = bh / Hh, h = bh - (bh / Hh) * Hh;
#pragma unroll
  for (int mf = 0; mf < 2; ++mf) {
    const float inv = 1.0f / lrun[mf];
    const int tg = q0 + w * 32 + mf * 16 + l15;
    float* orow = aout + (size_t)(b * Tt + tg) * Ee + h * Dd;
#pragma unroll
    for (int nd = 0; nd < 4; ++nd) {
      float4 ov;
      ov.x = oacc[mf][nd][0] * inv;
      ov.y = oacc[mf][nd][1] * inv;
      ov.z = oacc[mf][nd][2] * inv;
      ov.w = oacc[mf][nd][3] * inv;
      *(float4*)(orow + nd * 16 + l4 * 4) = ov;
    }
  }
}

// ---------------- residual(+residual2) + layernorm ----------------
__global__ __launch_bounds__(256) void ln_kernel(const float* __restrict__ a,
                                                 const float* __restrict__ b1r,
                                                 const float* __restrict__ b2r,
                                                 const float* __restrict__ g,
                                                 const float* __restrict__ beta,
                                                 float* __restrict__ yout,
                                                 u16* __restrict__ ybout) {
  const int m = blockIdx.x;
  const float* pa = a + (size_t)m * Ee;
  const float* pb = b1r + (size_t)m * Ee;
  const float* pc = b2r ? b2r + (size_t)m * Ee : nullptr;
  float vbuf[3];
  float s = 0.f, ss = 0.f;
#pragma unroll
  for (int i = 0; i < 3; ++i) {
    const int e = threadIdx.x + i * 256;
    float t = pa[e] + pb[e];
    if (pc) t += pc[e];
    vbuf[i] = t;
    s += t;
    ss += t * t;
  }
#pragma unroll
  for (int off = 32; off; off >>= 1) {
    s += __shfl_xor(s, off);
    ss += __shfl_xor(ss, off);
  }
  __shared__ float rs[8], rss[8];
  const int wv = threadIdx.x >> 6, ln = threadIdx.x & 63;
  if (ln == 0) { rs[wv] = s; rss[wv] = ss; }
  __syncthreads();
  if (threadIdx.x == 0) {
    float S = 0.f, SS = 0.f;
    for (int i = 0; i < 4; ++i) { S += rs[i]; SS += rss[i]; }
    rs[4] = S; rss[4] = SS;
  }
  __syncthreads();
  const float mu = rs[4] / Ee;
  const float var = rss[4] / Ee - mu * mu;
  const float inv = rsqrtf(var + 1e-5f);
#pragma unroll
  for (int i = 0; i < 3; ++i) {
    const int e = threadIdx.x + i * 256;
    const float t = (vbuf[i] - mu) * inv * g[e] + beta[e];
    yout[(size_t)m * Ee + e] = t;
    if (ybout) ybout[(size_t)m * Ee + e] = f2bf(t);
  }
}

// ---------------- launch ----------------
extern "C" void kernel_launch(void* const* d_in, const int* in_sizes, int n_in,
                              void* d_out, int out_size, void* d_ws, size_t ws_size,
                              hipStream_t stream) {
  const float* x  = (const float*)d_in[0];
  const float* Wq = (const float*)d_in[1];
  const float* Wk = (const float*)d_in[2];
  const float* Wv = (const float*)d_in[3];
  const float* W1 = (const float*)d_in[4];
  const float* b1 = (const float*)d_in[5];
  const float* W2 = (const float*)d_in[6];
  const float* b2 = (const float*)d_in[7];
  const float* g1 = (const float*)d_in[8];
  const float* be1 = (const float*)d_in[9];
  const float* g2 = (const float*)d_in[10];
  const float* be2 = (const float*)d_in[11];
  float* out = (float*)d_out;

  char* ws = (char*)d_ws;
  size_t off = 0;
  auto alloc = [&](size_t bytes) -> char* {
    char* p = ws + off;
    off += (bytes + 255) & ~(size_t)255;
    return p;
  };
  u16* xb    = (u16*)alloc((size_t)MROWS * Ee * 2);
  u16* wqkvt = (u16*)alloc((size_t)NQKV * Ee * 2);
  u16* w1t   = (u16*)alloc((size_t)HIDc * Ee * 2);
  u16* w2t   = (u16*)alloc((size_t)Ee * HIDc * 2);
  u16* qb    = (u16*)alloc((size_t)Bb * Hh * Tt * Dd * 2);
  u16* kb    = (u16*)alloc((size_t)Bb * Hh * Tt * Dd * 2);
  u16* vb    = (u16*)alloc((size_t)Bb * Hh * Tt * Dd * 2);   // [B,H,T,D]
  u16* vtb   = (u16*)alloc((size_t)Bb * Hh * Tt * Dd * 2);   // [B,H,D,T]
  float* attn = (float*)alloc((size_t)MROWS * Ee * 4);
  float* y    = (float*)alloc((size_t)MROWS * Ee * 4);
  u16* yb     = (u16*)alloc((size_t)MROWS * Ee * 2);
  u16* hbuf   = (u16*)alloc((size_t)MROWS * HIDc * 2);
  float* mlp  = (float*)alloc((size_t)2 * MROWS * Ee * 4);   // 2 split-K partials
  (void)ws_size;

  // 1. conversions (all coalesced)
  cvt_x_kernel<<<(MROWS * Ee / 4 + 255) / 256, 256, 0, stream>>>(x, xb, MROWS * Ee / 4);
  tr_qkv_kernel<<<dim3(2, 24, 36), 256, 0, stream>>>(Wq, Wk, Wv, wqkvt);
  tr_kernel<<<dim3(96, 24, 1), 256, 0, stream>>>(W1, w1t, Ee, HIDc);
  tr_kernel<<<dim3(24, 96, 1), 256, 0, stream>>>(W2, w2t, HIDc, Ee);

  // 2. QKV projection
  gemm_bt_kernel<0, 128, 1><<<18 * 32, 256, 0, stream>>>(
      xb, wqkvt, nullptr, nullptr, nullptr, qb, kb, vb, MROWS, NQKV, Ee, 18, 32);
  trv_kernel<<<dim3(32, 24), 256, 0, stream>>>(vb, vtb);

  // 3. attention
  attn_kernel<<<384, 256, 0, stream>>>(qb, kb, vtb, attn);

  // 4. LN1
  ln_kernel<<<MROWS, 256, 0, stream>>>(x, attn, nullptr, g1, be1, y, yb);

  // 5. MLP
  gemm_bt_kernel<1, 128, 1><<<24 * 32, 256, 0, stream>>>(
      yb, w1t, b1, hbuf, nullptr, nullptr, nullptr, nullptr, MROWS, HIDc, Ee, 24, 32);
  gemm_bt_kernel<2, 64, 2><<<12 * 32 * 2, 256, 0, stream>>>(
      hbuf, w2t, b2, nullptr, mlp, nullptr, nullptr, nullptr, MROWS, Ee, HIDc, 12, 32);

  // 6. LN2 (y + mlp0 + mlp1) -> output
  ln_kernel<<<MROWS, 256, 0, stream>>>(y, mlp, mlp + (size_t)MROWS * Ee, g2, be2, out, nullptr);
}

// Round 5
// 177.142 us; speedup vs baseline: 1.8476x; 1.0594x over previous
//
#include <hip/hip_runtime.h>
#include <stdint.h>

// Problem constants
constexpr int Ee   = 768;
constexpr int Hh   = 12;
constexpr int Dd   = 64;
constexpr int Tt   = 2048;
constexpr int Bb   = 2;
constexpr int HIDc = 3072;
constexpr int MROWS = Bb * Tt;        // 4096
constexpr int NQKV  = 3 * Hh * Dd;    // 2304

typedef unsigned short u16;
typedef __bf16 bf16;
typedef bf16 bf16x8 __attribute__((ext_vector_type(8)));
typedef float f32x4 __attribute__((ext_vector_type(4)));

__device__ __forceinline__ u16 f2bf(float f) {
  uint32_t u = __builtin_bit_cast(uint32_t, f);
  u += 0x7fffu + ((u >> 16) & 1u);
  return (u16)(u >> 16);
}

__device__ __forceinline__ uint32_t cvt_pk_bf16(float lo, float hi) {
  uint32_t r;
  asm("v_cvt_pk_bf16_f32 %0, %1, %2" : "=v"(r) : "v"(lo), "v"(hi));
  return r;
}

__device__ __forceinline__ f32x4 mfma16(bf16x8 a, bf16x8 b, f32x4 c) {
  return __builtin_amdgcn_mfma_f32_16x16x32_bf16(a, b, c, 0, 0, 0);
}

#define GLOAD_LDS16(gp, lp)                                                            \
  __builtin_amdgcn_global_load_lds((const __attribute__((address_space(1))) void*)(gp),\
                                   (__attribute__((address_space(3))) void*)(lp),      \
                                   16, 0, 0)

// XOR swizzle inside a 128-byte LDS row (T2, m201 pattern)
#define KSWZ(row, byte) ((row) * 128 + ((byte) ^ (((row) & 7) << 4)))

// ---------------- conversion / layout kernels ----------------

__global__ __launch_bounds__(256) void cvt_x_kernel(const float* __restrict__ in,
                                                    u16* __restrict__ out, int n4) {
  int i = blockIdx.x * 256 + threadIdx.x;
  if (i >= n4) return;
  const float4 f = *(const float4*)(in + (size_t)i * 4);
  uint2 o;
  u16* po = (u16*)&o;
  po[0] = f2bf(f.x); po[1] = f2bf(f.y); po[2] = f2bf(f.z); po[3] = f2bf(f.w);
  *(uint2*)(out + (size_t)i * 4) = o;
}

// tiled transpose: in[z][R][C] f32 -> out[z][C][R] bf16
__global__ __launch_bounds__(256) void tr_kernel(const float* __restrict__ in,
                                                 u16* __restrict__ out,
                                                 int R, int C) {
  __shared__ float t[32][33];
  const int tx = threadIdx.x & 31, ty = threadIdx.x >> 5;
  const int r0 = blockIdx.y * 32, c0 = blockIdx.x * 32;
  const float* ip = in + (size_t)blockIdx.z * R * C;
#pragma unroll
  for (int i = 0; i < 4; ++i)
    t[ty * 4 + i][tx] = ip[(size_t)(r0 + ty * 4 + i) * C + c0 + tx];
  __syncthreads();
  u16* op = out + (size_t)blockIdx.z * C * R;
#pragma unroll
  for (int i = 0; i < 4; ++i)
    op[(size_t)(c0 + ty * 4 + i) * R + r0 + tx] = f2bf(t[tx][ty * 4 + i]);
}

// Wq/Wk/Wv [12][768][64] f32 -> wqkvt [(which*768 + h*64 + d)][768] bf16
__global__ __launch_bounds__(256) void tr_qkv_kernel(const float* __restrict__ Wq,
                                                     const float* __restrict__ Wk,
                                                     const float* __restrict__ Wv,
                                                     u16* __restrict__ out) {
  __shared__ float t[32][33];
  const int tx = threadIdx.x & 31, ty = threadIdx.x >> 5;
  const int z = blockIdx.z;                 // 0..35
  const int which = z / 12, hs = z - which * 12;
  const float* W = (which == 0) ? Wq : (which == 1) ? Wk : Wv;
  const float* ip = W + (size_t)hs * Ee * Dd;              // [768][64] slice
  const int r0 = blockIdx.y * 32, c0 = blockIdx.x * 32;    // r over E, c over D
#pragma unroll
  for (int i = 0; i < 4; ++i)
    t[ty * 4 + i][tx] = ip[(size_t)(r0 + ty * 4 + i) * Dd + c0 + tx];
  __syncthreads();
  u16* op = out + ((size_t)which * 768 + hs * 64) * Ee;    // rows over D, cols over E
#pragma unroll
  for (int i = 0; i < 4; ++i)
    op[(size_t)(c0 + ty * 4 + i) * Ee + r0 + tx] = f2bf(t[tx][ty * 4 + i]);
}

// V [B*H][T][D] bf16 -> Vt [B*H][D][T] bf16
__global__ __launch_bounds__(256) void trv_kernel(const u16* __restrict__ in,
                                                  u16* __restrict__ out) {
  __shared__ u16 t[64][72];
  const int z = blockIdx.y;
  const int t0 = blockIdx.x * 64;
  const int tid = threadIdx.x;
#pragma unroll
  for (int it = 0; it < 2; ++it) {
    const int idx = it * 256 + tid;
    const int row = idx >> 3, c8 = (idx & 7) * 8;
    *(uint4*)&t[row][c8] = *(const uint4*)(in + ((size_t)z * Tt + t0 + row) * Dd + c8);
  }
  __syncthreads();
#pragma unroll
  for (int it = 0; it < 2; ++it) {
    const int idx = it * 256 + tid;
    const int d = idx >> 3, tt = (idx & 7) * 8;
    uint4 o;
    u16* po = (u16*)&o;
#pragma unroll
    for (int i = 0; i < 8; ++i) po[i] = t[tt + i][d];
    *(uint4*)(out + ((size_t)z * Dd + d) * Tt + t0 + tt) = o;
  }
}

// ---------------- GEMM: C[M,N] = A[M,K](bf16) * Bt[N,K](bf16)^T ----------------
// BK=64, XOR-swizzled LDS (T2, both-sides via inverse-swizzled global source).
// EPI 0: scatter to q/k/v [B,H,T,D] bf16
// EPI 1: +bias, relu, bf16 row-major out
// EPI 2: +bias(kz==0 only), fp32 out to partial buffer kz
template <int EPI, int BN, int SPLITK>
__global__ __launch_bounds__(256) void gemm_bt_kernel(
    const u16* __restrict__ A, const u16* __restrict__ Bt,
    const float* __restrict__ bias,
    u16* __restrict__ out_u, float* __restrict__ out_f,
    u16* __restrict__ qp, u16* __restrict__ kp, u16* __restrict__ vp,
    int Mdim, int Ndim, int Kdim, int gx, int gy) {
  constexpr int WN = BN / 64;          // waves along N (2 or 1)
  constexpr int WM = 4 / WN;           // waves along M (2 or 4)
  constexpr int MR = 128 / WM / 16;    // m-frags per wave (4 or 2)
  constexpr int ACH = 16;              // A chunks of 1KB
  constexpr int BCH = BN / 8;          // B chunks of 1KB
  __shared__ u16 la[128 * 64];
  __shared__ u16 lb[BN * 64];
  const int tid = threadIdx.x, lane = tid & 63, wv = tid >> 6;
  const int wm = wv / WN, wn = wv % WN;
  const int l15 = lane & 15, l4 = lane >> 4;

  // chunked XCD swizzle: consecutive wg on one XCD, bx fastest (A-panel reuse)
  const int nwg = gx * gy * SPLITK;
  const int cpx = nwg >> 3;
  const int wg = (blockIdx.x & 7) * cpx + (blockIdx.x >> 3);
  const int bx = wg % gx;
  const int byz = wg / gx;
  const int by = byz % gy;
  const int kz = byz / gy;
  const int m0 = by * 128, n0 = bx * BN;
  const int Ks = Kdim / SPLITK;
  const int kend = (kz + 1) * Ks;

  f32x4 acc[MR][4] = {};

  for (int k0 = kz * Ks; k0 < kend; k0 += 64) {
#pragma unroll
    for (int j = 0; j < ACH / 4; ++j) {
      const int cb = (wv * (ACH / 4) + j) * 64;
      const int ci = cb + lane;
      const int row = ci >> 3;
      const int kbl = ((ci & 7) * 16) ^ ((row & 7) << 4);
      GLOAD_LDS16(A + (size_t)(m0 + row) * Kdim + k0 + (kbl >> 1), la + (size_t)cb * 8);
    }
#pragma unroll
    for (int j = 0; j < BCH / 4; ++j) {
      const int cb = (wv * (BCH / 4) + j) * 64;
      const int ci = cb + lane;
      const int row = ci >> 3;
      const int kbl = ((ci & 7) * 16) ^ ((row & 7) << 4);
      GLOAD_LDS16(Bt + (size_t)(n0 + row) * Kdim + k0 + (kbl >> 1), lb + (size_t)cb * 8);
    }
    __syncthreads();
#pragma unroll
    for (int ks = 0; ks < 2; ++ks) {
      bf16x8 af[MR], bfr[4];
#pragma unroll
      for (int i = 0; i < MR; ++i) {
        const int row = wm * (MR * 16) + i * 16 + l15;
        af[i] = *(const bf16x8*)((const char*)la + row * 128 +
                                 (((ks * 64 + l4 * 16)) ^ ((row & 7) << 4)));
      }
#pragma unroll
      for (int i = 0; i < 4; ++i) {
        const int row = wn * 64 + i * 16 + l15;
        bfr[i] = *(const bf16x8*)((const char*)lb + row * 128 +
                                  (((ks * 64 + l4 * 16)) ^ ((row & 7) << 4)));
      }
#pragma unroll
      for (int mi = 0; mi < MR; ++mi)
#pragma unroll
        for (int ni = 0; ni < 4; ++ni)
          acc[mi][ni] = mfma16(af[mi], bfr[ni], acc[mi][ni]);
    }
    __syncthreads();
  }

#pragma unroll
  for (int mi = 0; mi < MR; ++mi)
#pragma unroll
    for (int ni = 0; ni < 4; ++ni)
#pragma unroll
      for (int r = 0; r < 4; ++r) {
        const int m = m0 + wm * (MR * 16) + mi * 16 + l4 * 4 + r;
        const int n = n0 + wn * 64 + ni * 16 + l15;
        float val = acc[mi][ni][r];
        if constexpr (EPI == 0) {
          const int b = m >> 11, t = m & 2047;
          const int which = n / (Hh * Dd);
          const int nn = n - which * (Hh * Dd);
          const int h = nn >> 6, d = nn & 63;
          u16* dst = (which == 0) ? qp : (which == 1) ? kp : vp;
          dst[((size_t)(b * Hh + h) * Tt + t) * Dd + d] = f2bf(val);
        } else if constexpr (EPI == 1) {
          val += bias[n];
          val = fmaxf(val, 0.0f);
          out_u[(size_t)m * Ndim + n] = f2bf(val);
        } else {
          if (kz == 0) val += bias[n];
          out_f[(size_t)kz * Mdim * Ndim + (size_t)m * Ndim + n] = val;
        }
      }
}

// ---------------- flash attention (swapped QK^T, in-register P, no-max) ----------
// QBLK=64: grid 768 = 24 bh x 32 q-tiles; 4 waves x 16 q-rows.
// XOR-swizzled [64][64] K and V^T tiles (T2); double-buffered; T14 reg-staging.
// bid: x8=bid&7 (XCD pin), kk=bid>>3, g=kk%3, qt=31-kk/3, bh=g*8+x8
__global__ __launch_bounds__(256) void attn_kernel(const u16* __restrict__ q,
                                                   const u16* __restrict__ k,
                                                   const u16* __restrict__ vtg,
                                                   float* __restrict__ aout) {
  __shared__ u16 kl[2][64 * 64];     // K tile [s][d], swizzled 128B rows
  __shared__ u16 vt[2][64 * 64];     // V^T tile [d][s], swizzled
  __shared__ u16 pl[4][16 * 64];     // per-wave P tile [t_loc][s], swizzled
  const int tid = threadIdx.x, lane = tid & 63, w = tid >> 6;
  const int l15 = lane & 15, l4 = lane >> 4;
  const int bid = blockIdx.x;
  const int x8 = bid & 7, kk2 = bid >> 3;
  const int g = kk2 % 3, qt = 31 - kk2 / 3;
  const int bh = g * 8 + x8;
  const int q0 = qt * 64;
  const int ntiles = qt + 1;
  constexpr float SC = 0.18033688f;   // log2(e)/8

  const u16* kgb = k + (size_t)bh * Tt * Dd;
  const u16* vgb = vtg + (size_t)bh * Dd * Tt;

  // Q fragments (16 rows x 64 d per wave); used as MFMA B operand
  bf16x8 qf[2];
#pragma unroll
  for (int kd = 0; kd < 2; ++kd)
    qf[kd] = *(const bf16x8*)(q + ((size_t)bh * Tt + q0 + w * 16 + l15) * Dd +
                              kd * 32 + l4 * 8);

  // staging: per thread 2x16B for K and 2x16B for V^T
  const int c0 = tid, c1 = tid + 256;
  const int row0 = c0 >> 3, cb0 = (c0 & 7) * 16;
  const int row1 = c1 >> 3, cb1 = (c1 & 7) * 16;
  const int lds0 = row0 * 128 + (cb0 ^ ((row0 & 7) << 4));
  const int lds1 = row1 * 128 + (cb1 ^ ((row1 & 7) << 4));
  const int gk0 = row0 * Dd + (c0 & 7) * 8;
  const int gk1 = row1 * Dd + (c1 & 7) * 8;
  const int gv0 = row0 * Tt + (c0 & 7) * 8;
  const int gv1 = row1 * Tt + (c1 & 7) * 8;

  // prologue: stage tile 0 into buffer 0
  {
    const uint4 ka  = *(const uint4*)(kgb + gk0);
    const uint4 kb2 = *(const uint4*)(kgb + gk1);
    const uint4 va  = *(const uint4*)(vgb + gv0);
    const uint4 vb2 = *(const uint4*)(vgb + gv1);
    *(uint4*)((char*)kl[0] + lds0) = ka;
    *(uint4*)((char*)kl[0] + lds1) = kb2;
    *(uint4*)((char*)vt[0] + lds0) = va;
    *(uint4*)((char*)vt[0] + lds1) = vb2;
  }

  f32x4 oacc[4] = {};
  float lrun = 0.f;
  u16* plw = &pl[w][0];

  for (int j = 0; j < ntiles; ++j) {
    __syncthreads();   // buf[j&1] writes visible; buf[(j+1)&1] readers done
    const int cur = j & 1;
    const bool more = (j + 1 < ntiles);
    uint4 ka, kb2, va, vb2;
    if (more) {        // T14: issue next-tile loads right after barrier
      const int s0n = (j + 1) * 64;
      ka  = *(const uint4*)(kgb + (size_t)s0n * Dd + gk0);
      kb2 = *(const uint4*)(kgb + (size_t)s0n * Dd + gk1);
      va  = *(const uint4*)(vgb + s0n + gv0);
      vb2 = *(const uint4*)(vgb + s0n + gv1);
    }
    const u16* klc = kl[cur];
    const u16* vtc = vt[cur];

    // ---- S^T = K Q^T: A=K-frag (rows s), B=Q-frag (cols t) ----
    f32x4 sacc[4] = {};
#pragma unroll
    for (int ns = 0; ns < 4; ++ns) {
      const int row = ns * 16 + l15;
      const bf16x8 kf0 = *(const bf16x8*)((const char*)klc + KSWZ(row, l4 * 16));
      const bf16x8 kf1 = *(const bf16x8*)((const char*)klc + KSWZ(row, 64 + l4 * 16));
      sacc[ns] = mfma16(kf0, qf[0], sacc[ns]);
      sacc[ns] = mfma16(kf1, qf[1], sacc[ns]);
    }

    // ---- P = exp2(S^T * SC) (no max), causal mask on diagonal tile ----
    const bool diag = (j == qt);
    const int tg = q0 + w * 16 + l15;
    float pe[16];
    float rs = 0.f;
#pragma unroll
    for (int ns = 0; ns < 4; ++ns)
#pragma unroll
      for (int r = 0; r < 4; ++r) {
        float e = __builtin_amdgcn_exp2f(sacc[ns][r] * SC);
        if (diag) {
          const int sg = j * 64 + ns * 16 + l4 * 4 + r;
          e = (sg > tg) ? 0.f : e;
        }
        pe[ns * 4 + r] = e;
        rs += e;
      }
    rs += __shfl_xor(rs, 16);
    rs += __shfl_xor(rs, 32);
    lrun += rs;
#pragma unroll
    for (int ns = 0; ns < 4; ++ns) {
      uint2 pw;
      pw.x = cvt_pk_bf16(pe[ns * 4 + 0], pe[ns * 4 + 1]);
      pw.y = cvt_pk_bf16(pe[ns * 4 + 2], pe[ns * 4 + 3]);
      *(uint2*)((char*)plw + KSWZ(l15, ns * 32 + l4 * 8)) = pw;
    }

    // ---- O^T += V^T P^T : A=V^T-frag (rows d), B=P-frag (cols t) ----
#pragma unroll
    for (int ks = 0; ks < 2; ++ks) {
      const bf16x8 pf = *(const bf16x8*)((const char*)plw + KSWZ(l15, ks * 64 + l4 * 16));
#pragma unroll
      for (int nd = 0; nd < 4; ++nd) {
        const int row = nd * 16 + l15;
        const bf16x8 vf = *(const bf16x8*)((const char*)vtc + KSWZ(row, ks * 64 + l4 * 16));
        oacc[nd] = mfma16(vf, pf, oacc[nd]);
      }
    }

    if (more) {   // write next tile into the other buffer (after this iter's reads)
      const int nxt = cur ^ 1;
      *(uint4*)((char*)kl[nxt] + lds0) = ka;
      *(uint4*)((char*)kl[nxt] + lds1) = kb2;
      *(uint4*)((char*)vt[nxt] + lds0) = va;
      *(uint4*)((char*)vt[nxt] + lds1) = vb2;
    }
  }

  // ---- normalize + store (O^T: lane has d = nd*16+l4*4+r, t = l15) ----
  const int b = bh / Hh, h = bh - (bh / Hh) * Hh;
  const float inv = 1.0f / lrun;
  const int tg = q0 + w * 16 + l15;
  float* orow = aout + (size_t)(b * Tt + tg) * Ee + h * Dd;
#pragma unroll
  for (int nd = 0; nd < 4; ++nd) {
    float4 ov;
    ov.x = oacc[nd][0] * inv;
    ov.y = oacc[nd][1] * inv;
    ov.z = oacc[nd][2] * inv;
    ov.w = oacc[nd][3] * inv;
    *(float4*)(orow + nd * 16 + l4 * 4) = ov;
  }
}

// ---------------- residual(+residual2) + layernorm ----------------
__global__ __launch_bounds__(256) void ln_kernel(const float* __restrict__ a,
                                                 const float* __restrict__ b1r,
                                                 const float* __restrict__ b2r,
                                                 const float* __restrict__ g,
                                                 const float* __restrict__ beta,
                                                 float* __restrict__ yout,
                                                 u16* __restrict__ ybout) {
  const int m = blockIdx.x;
  const float* pa = a + (size_t)m * Ee;
  const float* pb = b1r + (size_t)m * Ee;
  const float* pc = b2r ? b2r + (size_t)m * Ee : nullptr;
  float vbuf[3];
  float s = 0.f, ss = 0.f;
#pragma unroll
  for (int i = 0; i < 3; ++i) {
    const int e = threadIdx.x + i * 256;
    float t = pa[e] + pb[e];
    if (pc) t += pc[e];
    vbuf[i] = t;
    s += t;
    ss += t * t;
  }
#pragma unroll
  for (int off = 32; off; off >>= 1) {
    s += __shfl_xor(s, off);
    ss += __shfl_xor(ss, off);
  }
  __shared__ float rs[8], rss[8];
  const int wv = threadIdx.x >> 6, ln = threadIdx.x & 63;
  if (ln == 0) { rs[wv] = s; rss[wv] = ss; }
  __syncthreads();
  if (threadIdx.x == 0) {
    float S = 0.f, SS = 0.f;
    for (int i = 0; i < 4; ++i) { S += rs[i]; SS += rss[i]; }
    rs[4] = S; rss[4] = SS;
  }
  __syncthreads();
  const float mu = rs[4] / Ee;
  const float var = rss[4] / Ee - mu * mu;
  const float inv = rsqrtf(var + 1e-5f);
#pragma unroll
  for (int i = 0; i < 3; ++i) {
    const int e = threadIdx.x + i * 256;
    const float t = (vbuf[i] - mu) * inv * g[e] + beta[e];
    yout[(size_t)m * Ee + e] = t;
    if (ybout) ybout[(size_t)m * Ee + e] = f2bf(t);
  }
}

// ---------------- launch ----------------
extern "C" void kernel_launch(void* const* d_in, const int* in_sizes, int n_in,
                              void* d_out, int out_size, void* d_ws, size_t ws_size,
                              hipStream_t stream) {
  const float* x  = (const float*)d_in[0];
  const float* Wq = (const float*)d_in[1];
  const float* Wk = (const float*)d_in[2];
  const float* Wv = (const float*)d_in[3];
  const float* W1 = (const float*)d_in[4];
  const float* b1 = (const float*)d_in[5];
  const float* W2 = (const float*)d_in[6];
  const float* b2 = (const float*)d_in[7];
  const float* g1 = (const float*)d_in[8];
  const float* be1 = (const float*)d_in[9];
  const float* g2 = (const float*)d_in[10];
  const float* be2 = (const float*)d_in[11];
  float* out = (float*)d_out;

  char* ws = (char*)d_ws;
  size_t off = 0;
  auto alloc = [&](size_t bytes) -> char* {
    char* p = ws + off;
    off += (bytes + 255) & ~(size_t)255;
    return p;
  };
  u16* xb    = (u16*)alloc((size_t)MROWS * Ee * 2);
  u16* wqkvt = (u16*)alloc((size_t)NQKV * Ee * 2);
  u16* w1t   = (u16*)alloc((size_t)HIDc * Ee * 2);
  u16* w2t   = (u16*)alloc((size_t)Ee * HIDc * 2);
  u16* qb    = (u16*)alloc((size_t)Bb * Hh * Tt * Dd * 2);
  u16* kb    = (u16*)alloc((size_t)Bb * Hh * Tt * Dd * 2);
  u16* vb    = (u16*)alloc((size_t)Bb * Hh * Tt * Dd * 2);   // [B,H,T,D]
  u16* vtb   = (u16*)alloc((size_t)Bb * Hh * Tt * Dd * 2);   // [B,H,D,T]
  float* attn = (float*)alloc((size_t)MROWS * Ee * 4);
  float* y    = (float*)alloc((size_t)MROWS * Ee * 4);
  u16* yb     = (u16*)alloc((size_t)MROWS * Ee * 2);
  u16* hbuf   = (u16*)alloc((size_t)MROWS * HIDc * 2);
  float* mlp  = (float*)alloc((size_t)2 * MROWS * Ee * 4);   // 2 split-K partials
  (void)ws_size;

  // 1. conversions (all coalesced)
  cvt_x_kernel<<<(MROWS * Ee / 4 + 255) / 256, 256, 0, stream>>>(x, xb, MROWS * Ee / 4);
  tr_qkv_kernel<<<dim3(2, 24, 36), 256, 0, stream>>>(Wq, Wk, Wv, wqkvt);
  tr_kernel<<<dim3(96, 24, 1), 256, 0, stream>>>(W1, w1t, Ee, HIDc);
  tr_kernel<<<dim3(24, 96, 1), 256, 0, stream>>>(W2, w2t, HIDc, Ee);

  // 2. QKV projection
  gemm_bt_kernel<0, 128, 1><<<18 * 32, 256, 0, stream>>>(
      xb, wqkvt, nullptr, nullptr, nullptr, qb, kb, vb, MROWS, NQKV, Ee, 18, 32);
  trv_kernel<<<dim3(32, 24), 256, 0, stream>>>(vb, vtb);

  // 3. attention
  attn_kernel<<<768, 256, 0, stream>>>(qb, kb, vtb, attn);

  // 4. LN1
  ln_kernel<<<MROWS, 256, 0, stream>>>(x, attn, nullptr, g1, be1, y, yb);

  // 5. MLP
  gemm_bt_kernel<1, 128, 1><<<24 * 32, 256, 0, stream>>>(
      yb, w1t, b1, hbuf, nullptr, nullptr, nullptr, nullptr, MROWS, HIDc, Ee, 24, 32);
  gemm_bt_kernel<2, 64, 2><<<12 * 32 * 2, 256, 0, stream>>>(
      hbuf, w2t, b2, nullptr, mlp, nullptr, nullptr, nullptr, MROWS, Ee, HIDc, 12, 32);

  // 6. LN2 (y + mlp0 + mlp1) -> output
  ln_kernel<<<MROWS, 256, 0, stream>>>(y, mlp, mlp + (size_t)MROWS * Ee, g2, be2, out, nullptr);
}